// Round 1
// baseline (364.267 us; speedup 1.0000x reference)
//
#include <hip/hip_runtime.h>

// GAT, 2 layers, H=2 heads, D=C=128, concat=False (head mean), L2 normalize after each layer.
// Float tensors: fp32 OR bf16 (runtime-probed). edge_index: int32 OR int64 (runtime-probed).
// Internal h-matrix bf16 row-major [N][256].
// R11: k_aggregate gather rewritten as 3-slot software pipeline in a wave-uniform counted
// loop (deg is uniform per wave): 2 groups of row-loads in flight, zero register-shift movs,
// unconditional FMAs (inactive edges carry weight==0, slots zero-initialized).
// k_spillfix: uniform early-out when no spills occurred.

#define CAP 48
#define SPILLCAP 65536

using short8  = __attribute__((ext_vector_type(8))) short;
using float4v = __attribute__((ext_vector_type(4))) float;

static __device__ __forceinline__ float bf2f(unsigned int u16) {
    union { unsigned int i; float f; } v; v.i = u16 << 16; return v.f;
}
static __device__ __forceinline__ float bflo(unsigned int p){
    union { unsigned int i; float f; } v; v.i = p << 16; return v.f;
}
static __device__ __forceinline__ float bfhi(unsigned int p){
    union { unsigned int i; float f; } v; v.i = p & 0xffff0000u; return v.f;
}
static __device__ __forceinline__ unsigned short f2bf(float f) {
    union { float f; unsigned int i; } v; v.f = f;
    unsigned int x = v.i;
    x += 0x7fffu + ((x >> 16) & 1u);   // RNE
    return (unsigned short)(x >> 16);
}
static __device__ __forceinline__ float leaky(float x){ return x > 0.f ? x : 0.2f * x; }

// ---------------- probe dtypes + zero cnt/spillcnt (fused) ----------------
__global__ __launch_bounds__(256) void k_probe_zero(const unsigned int* __restrict__ xw,
                                                    const int* __restrict__ ei,
                                                    int* __restrict__ flags,
                                                    int* __restrict__ cnt, int N) {
    int i = blockIdx.x * 256 + threadIdx.x;
    if (i < N) cnt[i] = 0;
    if (blockIdx.x == 0) {
        __shared__ int insane, oddnz;
        int t = threadIdx.x;
        if (t == 0) { insane = 0; oddnz = 0; }
        __syncthreads();
        unsigned int w = xw[t];
        if (((w >> 7) & 0xFFu) >= 154u) atomicOr(&insane, 1);
        if (ei[2 * t + 1] != 0) atomicOr(&oddnz, 1);
        __syncthreads();
        if (t == 0) { flags[0] = insane ? 1 : 0; flags[1] = oddnz ? 0 : 1; flags[2] = 0; }
    }
}

// ---------------- W -> WT (bf16): WT[l][n][k] = W[l][k][n] ----------------
__global__ __launch_bounds__(256) void k_transpose(const void* __restrict__ W,
                                                   unsigned short* __restrict__ WT,
                                                   const int* __restrict__ flags) {
    int fx = flags[0];
    int idx = blockIdx.x * 256 + threadIdx.x;
    int layer = idx >> 15;
    int rem = idx & 32767;
    int k = rem >> 8, n = rem & 255;
    int srci = layer * 32768 + k * 256 + n;
    unsigned short v;
    if (fx) v = f2bf(((const float*)W)[srci]);
    else    v = ((const unsigned short*)W)[srci];
    WT[layer * 32768 + n * 128 + k] = v;
}

// ---------------- single-pass bucket scatter ----------------
static __device__ __forceinline__ int edge_dst(const int* ei, int E, int i, int is64) {
    return is64 ? ei[2 * E + 2 * i] : ei[E + i];
}
static __device__ __forceinline__ int edge_src(const int* ei, int E, int i, int is64) {
    return is64 ? ei[2 * i] : ei[i];
}

__global__ __launch_bounds__(256) void k_bucket(const int* __restrict__ ei, int E, int N,
                                                int* __restrict__ flags,
                                                int* __restrict__ cnt,
                                                int* __restrict__ bucket,
                                                int* __restrict__ spill) {
    int i = blockIdx.x * 256 + threadIdx.x;
    if (i >= E + N) return;
    int src, dst;
    if (i < E) {
        int is64 = flags[1];
        src = edge_src(ei, E, i, is64);
        dst = edge_dst(ei, E, i, is64);
        if ((unsigned)src >= (unsigned)N) src = 0;
        if ((unsigned)dst >= (unsigned)N) dst = 0;
    } else src = dst = i - E;   // self loop
    int pos = atomicAdd(&cnt[dst], 1);
    if (pos < CAP) {
        bucket[dst * CAP + pos] = src;
    } else {
        int sp = atomicAdd(&flags[2], 1);
        if (sp < SPILLCAP) { spill[2 * sp] = dst; spill[2 * sp + 1] = src; }
    }
}

// ---------------- fused GEMM + alpha (R8-proven) ----------------
__global__ __launch_bounds__(256) void k_gemm_alpha(const void* __restrict__ X,
                                                    const unsigned short* __restrict__ WT,
                                                    const void* __restrict__ atts,
                                                    const void* __restrict__ attd,
                                                    int layer,
                                                    unsigned short* __restrict__ Hb,
                                                    float* __restrict__ as_, float* __restrict__ ad_,
                                                    int N, const int* __restrict__ flags) {
    __shared__ float lds_s[4][16], lds_d[4][16];
    __shared__ unsigned short cbuf[4][16][72];
    int fx = flags[0];
    int mt = blockIdx.x;
    int wave = threadIdx.x >> 6;
    int lane = threadIdx.x & 63;
    int r16 = lane & 15, quad = lane >> 4;
    int m0 = mt << 4;
    int arow = m0 + r16; if (arow >= N) arow = N - 1;
    short8 a[4];
    if (fx) {
        const float* Xf = (const float*)X;
#pragma unroll
        for (int kk = 0; kk < 4; kk++) {
            const float4v* pv = (const float4v*)(Xf + (size_t)arow * 128 + kk * 32 + quad * 8);
            float4v lo = pv[0], hi = pv[1];
            short8 t;
            t[0] = (short)f2bf(lo[0]); t[1] = (short)f2bf(lo[1]);
            t[2] = (short)f2bf(lo[2]); t[3] = (short)f2bf(lo[3]);
            t[4] = (short)f2bf(hi[0]); t[5] = (short)f2bf(hi[1]);
            t[6] = (short)f2bf(hi[2]); t[7] = (short)f2bf(hi[3]);
            a[kk] = t;
        }
    } else {
        const unsigned short* Xh = (const unsigned short*)X;
#pragma unroll
        for (int kk = 0; kk < 4; kk++)
            a[kk] = *(const short8*)(Xh + (size_t)arow * 128 + kk * 32 + quad * 8);
    }
    int head = wave >> 1;
    float ps[4] = {0.f, 0.f, 0.f, 0.f}, pd[4] = {0.f, 0.f, 0.f, 0.f};
#pragma unroll
    for (int nn = 0; nn < 4; nn++) {
        int nt = wave * 4 + nn;
        float4v acc = {0.f, 0.f, 0.f, 0.f};
#pragma unroll
        for (int kk = 0; kk < 4; kk++) {
            short8 b = *(const short8*)(WT + (nt * 16 + r16) * 128 + kk * 32 + quad * 8);
            acc = __builtin_amdgcn_mfma_f32_16x16x32_bf16(a[kk], b, acc, 0, 0, 0);
        }
        int c = (nt * 16 + r16) & 127;
        float sa, da;
        if (fx) {
            sa = ((const float*)atts)[layer * 256 + head * 128 + c];
            da = ((const float*)attd)[layer * 256 + head * 128 + c];
        } else {
            sa = bf2f(((const unsigned short*)atts)[layer * 256 + head * 128 + c]);
            da = bf2f(((const unsigned short*)attd)[layer * 256 + head * 128 + c]);
        }
#pragma unroll
        for (int r = 0; r < 4; r++) {
            cbuf[wave][quad * 4 + r][nn * 16 + r16] = f2bf(acc[r]);   // C/D: col=lane&15, row=quad*4+r [m89]
            ps[r] += acc[r] * sa;
            pd[r] += acc[r] * da;
        }
    }
#pragma unroll
    for (int it = 0; it < 2; it++) {
        int idx = it * 64 + lane;
        int row = idx >> 3, chunk = idx & 7;
        uint4 v = *(const uint4*)&cbuf[wave][row][chunk * 8];
        int grow = m0 + row;
        if (grow < N)
            *(uint4*)(Hb + (size_t)grow * 256 + wave * 64 + chunk * 8) = v;
    }
#pragma unroll
    for (int m = 1; m < 16; m <<= 1) {
#pragma unroll
        for (int r = 0; r < 4; r++) {
            ps[r] += __shfl_xor(ps[r], m);
            pd[r] += __shfl_xor(pd[r], m);
        }
    }
    if (r16 == 0) {
#pragma unroll
        for (int r = 0; r < 4; r++) {
            lds_s[wave][quad * 4 + r] = ps[r];
            lds_d[wave][quad * 4 + r] = pd[r];
        }
    }
    __syncthreads();
    if (threadIdx.x < 16) {
        int row = m0 + threadIdx.x;
        if (row < N) {
            float2 sv = { lds_s[0][threadIdx.x] + lds_s[1][threadIdx.x],
                          lds_s[2][threadIdx.x] + lds_s[3][threadIdx.x] };
            float2 dv = { lds_d[0][threadIdx.x] + lds_d[1][threadIdx.x],
                          lds_d[2][threadIdx.x] + lds_d[3][threadIdx.x] };
            *(float2*)(as_ + 2 * row) = sv;
            *(float2*)(ad_ + 2 * row) = dv;
        }
    }
}

// ---------------- hot aggregate: deg<=CAP only; 3-slot pipelined gather ----------------
static __device__ __forceinline__ void acc8(float* A, float w, uint4 q) {
    A[0] += w * bflo(q.x); A[1] += w * bfhi(q.x);
    A[2] += w * bflo(q.y); A[3] += w * bfhi(q.y);
    A[4] += w * bflo(q.z); A[5] += w * bfhi(q.z);
    A[6] += w * bflo(q.w); A[7] += w * bfhi(q.w);
}

__global__ __launch_bounds__(256) void k_aggregate(const unsigned short* __restrict__ Hb,
                                                   const float* __restrict__ as_, const float* __restrict__ ad_,
                                                   const int* __restrict__ cnt, const int* __restrict__ bucket,
                                                   const void* __restrict__ bias, int layer,
                                                   const int* __restrict__ flags,
                                                   void* __restrict__ outp, int N) {
    int fx = flags[0];
    int n = blockIdx.x * 4 + (threadIdx.x >> 6);
    if (n >= N) return;
    int deg = cnt[n];                // wave-uniform
    if (deg > CAP) return;           // handled by k_spillfix
    int lane = threadIdx.x & 63;
    int g = lane >> 4;
    int gl = lane & 15;              // owns channels [gl*8, gl*8+8) of each head
    const int* eb = bucket + n * CAP;
    float2 adv = *(const float2*)(ad_ + 2 * n);
    float ad0 = adv.x, ad1 = adv.y;

    // softmax over bucket (single sweep: deg <= 48 <= 64 lanes)
    bool act = lane < deg;
    int s = 0; float l0 = -1e30f, l1 = -1e30f;
    if (act) {
        s = eb[lane]; if ((unsigned)s >= (unsigned)N) s = 0;
        float2 av = *(const float2*)(as_ + 2 * s);
        l0 = leaky(av.x + ad0); l1 = leaky(av.y + ad1);
    }
    float m0 = l0, m1 = l1;
#pragma unroll
    for (int m = 1; m < 64; m <<= 1) { m0 = fmaxf(m0, __shfl_xor(m0, m)); m1 = fmaxf(m1, __shfl_xor(m1, m)); }
    float w0 = act ? __expf(l0 - m0) : 0.f;   // weight==0 for lanes >= deg -> padded stages add exact 0
    float w1 = act ? __expf(l1 - m1) : 0.f;
    float z0 = w0, z1 = w1;
#pragma unroll
    for (int m = 1; m < 64; m <<= 1) { z0 += __shfl_xor(z0, m); z1 += __shfl_xor(z1, m); }

    // 3-slot pipelined gather over groups of 4 edges. deg is wave-uniform, so the loop
    // is uniform (no divergent while). Slot X consumes group j then refills with group
    // j+3 in place -> ~2 stages of load slack, no register-shift movs.
    float acc0[8] = {0,0,0,0,0,0,0,0}, acc1[8] = {0,0,0,0,0,0,0,0};
    uint4 qA0 = {0,0,0,0}, qA1 = {0,0,0,0};
    uint4 qB0 = {0,0,0,0}, qB1 = {0,0,0,0};
    uint4 qC0 = {0,0,0,0}, qC1 = {0,0,0,0};
    int eA = g, eB = g + 4, eC = g + 8;
    float wA0, wA1, wB0, wB1, wC0, wC1;

    auto refill = [&](float& W0, float& W1, uint4& Q0, uint4& Q1, int E) {
        W0 = __shfl(w0, E); W1 = __shfl(w1, E);
        int s2 = __shfl(s, E);
        if (E < deg) {
            const unsigned short* row = Hb + ((size_t)s2 << 8) + gl * 8;
            Q0 = *(const uint4*)row;
            Q1 = *(const uint4*)(row + 128);
        }
    };
    refill(wA0, wA1, qA0, qA1, eA);
    refill(wB0, wB1, qB0, qB1, eB);
    refill(wC0, wC1, qC0, qC1, eC);

    int ngroups = (deg + 3) >> 2;    // uniform; <= 12
    for (int j = 0; j < ngroups; j += 3) {
        acc8(acc0, wA0, qA0); acc8(acc1, wA1, qA1);
        eA += 12; refill(wA0, wA1, qA0, qA1, eA);
        acc8(acc0, wB0, qB0); acc8(acc1, wB1, qB1);
        eB += 12; refill(wB0, wB1, qB0, qB1, eB);
        acc8(acc0, wC0, qC0); acc8(acc1, wC1, qC1);
        eC += 12; refill(wC0, wC1, qC0, qC1, eC);
    }

    float inv0 = 1.f / (z0 + 1e-16f), inv1 = 1.f / (z1 + 1e-16f);
#pragma unroll
    for (int k = 0; k < 8; k++) {
        acc0[k] += __shfl_xor(acc0[k], 16); acc0[k] += __shfl_xor(acc0[k], 32);
        acc1[k] += __shfl_xor(acc1[k], 16); acc1[k] += __shfl_xor(acc1[k], 32);
    }

    float vv[8];
    if (fx) {
        const float* bf = (const float*)bias + layer * 128 + gl * 8;
#pragma unroll
        for (int k = 0; k < 8; k++) vv[k] = 0.5f * (acc0[k] * inv0 + acc1[k] * inv1) + bf[k];
    } else {
        const unsigned short* bh = (const unsigned short*)bias + layer * 128 + gl * 8;
        uint4 bv = *(const uint4*)bh;
        float bfv[8] = { bflo(bv.x), bfhi(bv.x), bflo(bv.y), bfhi(bv.y),
                         bflo(bv.z), bfhi(bv.z), bflo(bv.w), bfhi(bv.w) };
#pragma unroll
        for (int k = 0; k < 8; k++) vv[k] = 0.5f * (acc0[k] * inv0 + acc1[k] * inv1) + bfv[k];
    }

    float ss = 0.f;
#pragma unroll
    for (int k = 0; k < 8; k++) ss += vv[k] * vv[k];
#pragma unroll
    for (int m = 1; m < 16; m <<= 1) ss += __shfl_xor(ss, m);
    float inv = 1.f / fmaxf(sqrtf(ss), 1e-12f);

    if (lane < 16) {
        if (fx) {
            float* op = (float*)outp + (size_t)n * 128 + gl * 8;
            float4 o0 = { vv[0] * inv, vv[1] * inv, vv[2] * inv, vv[3] * inv };
            float4 o1 = { vv[4] * inv, vv[5] * inv, vv[6] * inv, vv[7] * inv };
            *(float4*)op = o0;
            *(float4*)(op + 4) = o1;
        } else {
            unsigned short* op = (unsigned short*)outp + (size_t)n * 128 + gl * 8;
            uint4 pk;
            pk.x = (unsigned int)f2bf(vv[0] * inv) | ((unsigned int)f2bf(vv[1] * inv) << 16);
            pk.y = (unsigned int)f2bf(vv[2] * inv) | ((unsigned int)f2bf(vv[3] * inv) << 16);
            pk.z = (unsigned int)f2bf(vv[4] * inv) | ((unsigned int)f2bf(vv[5] * inv) << 16);
            pk.w = (unsigned int)f2bf(vv[6] * inv) | ((unsigned int)f2bf(vv[7] * inv) << 16);
            *(uint4*)op = pk;
        }
    }
}

// ---------------- spill fix: only nodes with deg > CAP (statistically never) ----------------
__global__ __launch_bounds__(256) void k_spillfix(const unsigned short* __restrict__ Hb,
                                                  const float* __restrict__ as_, const float* __restrict__ ad_,
                                                  const int* __restrict__ cnt, const int* __restrict__ bucket,
                                                  const int* __restrict__ spill, const int* __restrict__ flags,
                                                  const void* __restrict__ bias, int layer,
                                                  void* __restrict__ outp, int N) {
    if (flags[2] == 0) return;       // no spills anywhere: hot kernel covered every node
    int fx = flags[0];
    int n = blockIdx.x * 4 + (threadIdx.x >> 6);
    if (n >= N) return;
    int deg = cnt[n];
    if (deg <= CAP) return;          // hot kernel handled it
    int lane = threadIdx.x & 63;
    int g = lane >> 4;
    int gl = lane & 15;
    const int* eb = bucket + n * CAP;
    int sc = flags[2]; if (sc > SPILLCAP) sc = SPILLCAP;
    float2 adv = *(const float2*)(ad_ + 2 * n);
    float ad0 = adv.x, ad1 = adv.y;

    float m0 = -1e30f, m1 = -1e30f;
    for (int i = lane; i < CAP; i += 64) {
        int s = eb[i]; if ((unsigned)s >= (unsigned)N) s = 0;
        float2 av = *(const float2*)(as_ + 2 * s);
        m0 = fmaxf(m0, leaky(av.x + ad0));
        m1 = fmaxf(m1, leaky(av.y + ad1));
    }
    for (int i = lane; i < sc; i += 64) {
        if (spill[2 * i] == n) {
            int s = spill[2 * i + 1]; if ((unsigned)s >= (unsigned)N) s = 0;
            float2 av = *(const float2*)(as_ + 2 * s);
            m0 = fmaxf(m0, leaky(av.x + ad0));
            m1 = fmaxf(m1, leaky(av.y + ad1));
        }
    }
#pragma unroll
    for (int m = 1; m < 64; m <<= 1) { m0 = fmaxf(m0, __shfl_xor(m0, m)); m1 = fmaxf(m1, __shfl_xor(m1, m)); }

    float acc0[8] = {0,0,0,0,0,0,0,0}, acc1[8] = {0,0,0,0,0,0,0,0};
    float z0 = 0.f, z1 = 0.f;
    {
        bool act = lane < CAP;
        int s = 0; float w0 = 0.f, w1 = 0.f;
        if (act) {
            s = eb[lane]; if ((unsigned)s >= (unsigned)N) s = 0;
            float2 av = *(const float2*)(as_ + 2 * s);
            w0 = __expf(leaky(av.x + ad0) - m0);
            w1 = __expf(leaky(av.y + ad1) - m1);
            z0 += w0; z1 += w1;
        }
        for (int j = 0; 4 * j < CAP; j++) {
            int e = 4 * j + g;
            int sq    = __shfl(s, e);
            float wq0 = __shfl(w0, e);
            float wq1 = __shfl(w1, e);
            if (e < CAP) {
                const unsigned short* row = Hb + ((size_t)sq << 8);
                uint4 q0 = *(const uint4*)(row + gl * 8);
                uint4 q1 = *(const uint4*)(row + 128 + gl * 8);
                acc8(acc0, wq0, q0);
                acc8(acc1, wq1, q1);
            }
        }
    }
    for (int i = 0; i < sc; i++) {
        int d = spill[2 * i];
        if (d != n) continue;
        int s = spill[2 * i + 1]; if ((unsigned)s >= (unsigned)N) s = 0;
        float2 av = *(const float2*)(as_ + 2 * s);
        float w0 = __expf(leaky(av.x + ad0) - m0);
        float w1 = __expf(leaky(av.y + ad1) - m1);
        if (lane == 0) { z0 += w0; z1 += w1; }
        if (g == 0) {
            const unsigned short* row = Hb + ((size_t)s << 8);
            uint4 q0 = *(const uint4*)(row + gl * 8);
            uint4 q1 = *(const uint4*)(row + 128 + gl * 8);
            acc8(acc0, w0, q0);
            acc8(acc1, w1, q1);
        }
    }
#pragma unroll
    for (int m = 1; m < 64; m <<= 1) { z0 += __shfl_xor(z0, m); z1 += __shfl_xor(z1, m); }

    float inv0 = 1.f / (z0 + 1e-16f), inv1 = 1.f / (z1 + 1e-16f);
#pragma unroll
    for (int k = 0; k < 8; k++) {
        acc0[k] += __shfl_xor(acc0[k], 16); acc0[k] += __shfl_xor(acc0[k], 32);
        acc1[k] += __shfl_xor(acc1[k], 16); acc1[k] += __shfl_xor(acc1[k], 32);
    }
    float vv[8];
    if (fx) {
        const float* bf = (const float*)bias + layer * 128 + gl * 8;
#pragma unroll
        for (int k = 0; k < 8; k++) vv[k] = 0.5f * (acc0[k] * inv0 + acc1[k] * inv1) + bf[k];
    } else {
        const unsigned short* bh = (const unsigned short*)bias + layer * 128 + gl * 8;
        uint4 bv = *(const uint4*)bh;
        float bfv[8] = { bflo(bv.x), bfhi(bv.x), bflo(bv.y), bfhi(bv.y),
                         bflo(bv.z), bfhi(bv.z), bflo(bv.w), bfhi(bv.w) };
#pragma unroll
        for (int k = 0; k < 8; k++) vv[k] = 0.5f * (acc0[k] * inv0 + acc1[k] * inv1) + bfv[k];
    }
    float ss = 0.f;
#pragma unroll
    for (int k = 0; k < 8; k++) ss += vv[k] * vv[k];
#pragma unroll
    for (int m = 1; m < 16; m <<= 1) ss += __shfl_xor(ss, m);
    float inv = 1.f / fmaxf(sqrtf(ss), 1e-12f);
    if (lane < 16) {
        if (fx) {
            float* op = (float*)outp + (size_t)n * 128 + gl * 8;
            float4 o0 = { vv[0] * inv, vv[1] * inv, vv[2] * inv, vv[3] * inv };
            float4 o1 = { vv[4] * inv, vv[5] * inv, vv[6] * inv, vv[7] * inv };
            *(float4*)op = o0;
            *(float4*)(op + 4) = o1;
        } else {
            unsigned short* op = (unsigned short*)outp + (size_t)n * 128 + gl * 8;
            uint4 pk;
            pk.x = (unsigned int)f2bf(vv[0] * inv) | ((unsigned int)f2bf(vv[1] * inv) << 16);
            pk.y = (unsigned int)f2bf(vv[2] * inv) | ((unsigned int)f2bf(vv[3] * inv) << 16);
            pk.z = (unsigned int)f2bf(vv[4] * inv) | ((unsigned int)f2bf(vv[5] * inv) << 16);
            pk.w = (unsigned int)f2bf(vv[6] * inv) | ((unsigned int)f2bf(vv[7] * inv) << 16);
            *(uint4*)op = pk;
        }
    }
}

extern "C" void kernel_launch(void* const* d_in, const int* in_sizes, int n_in,
                              void* d_out, int out_size, void* d_ws, size_t ws_size,
                              hipStream_t stream) {
    const void* x    = d_in[0];
    const int*  ei   = (const int*)d_in[1];
    const void* W    = d_in[2];
    const void* atts = d_in[3];
    const void* attd = d_in[4];
    const void* bias = d_in[5];

    int N = in_sizes[0] / 128;
    int E = in_sizes[1] / 2;

    char* p = (char*)d_ws;
    auto alloc = [&](size_t bytes) -> char* {
        char* q = p; p += (bytes + 255) & ~(size_t)255; return q;
    };
    int* flags   = (int*)alloc(256);                                   // [0]=fx [1]=is64 [2]=spillcnt
    int* cnt     = (int*)alloc((size_t)N * 4);
    float* as_   = (float*)alloc((size_t)N * 2 * 4);
    float* ad_   = (float*)alloc((size_t)N * 2 * 4);
    unsigned short* wt = (unsigned short*)alloc(2 * 256 * 128 * 2);
    int* spill   = (int*)alloc((size_t)SPILLCAP * 2 * 4);              // 512 KB
    int* bucket  = (int*)alloc((size_t)N * CAP * 4);                   // 9.6 MB
    unsigned short* hbuf = (unsigned short*)alloc((size_t)N * 256 * 2);// 25.6 MB
    // total ~36.9 MB

    k_probe_zero<<<(N + 255) / 256, 256, 0, stream>>>((const unsigned int*)x, ei, flags, cnt, N);
    k_bucket<<<(E + N + 255) / 256, 256, 0, stream>>>(ei, E, N, flags, cnt, bucket, spill);
    k_transpose<<<256, 256, 0, stream>>>(W, wt, flags);

    int mtiles = (N + 15) / 16;
    int ngrp = (N + 3) / 4;
    for (int l = 0; l < 2; l++) {
        const void* xin = (l == 0) ? x : (const void*)d_out;
        k_gemm_alpha<<<mtiles, 256, 0, stream>>>(xin, wt + l * 32768, atts, attd, l,
                                                 hbuf, as_, ad_, N, flags);
        k_aggregate<<<ngrp, 256, 0, stream>>>(hbuf, as_, ad_, cnt, bucket,
                                              bias, l, flags, d_out, N);
        k_spillfix<<<ngrp, 256, 0, stream>>>(hbuf, as_, ad_, cnt, bucket, spill, flags,
                                             bias, l, d_out, N);
    }
}

// Round 3
// 357.155 us; speedup vs baseline: 1.0199x; 1.0199x over previous
//
#include <hip/hip_runtime.h>

// GAT, 2 layers, H=2 heads, D=C=128, concat=False (head mean), L2 normalize after each layer.
// Float tensors: fp32 OR bf16 (runtime-probed). edge_index: int32 OR int64 (runtime-probed).
// Internal h-matrix bf16 row-major [N][256].
// R13 == R12 resubmitted (previous round was an infra failure, no measurement).
// R12: R10's proven divergent-while gather (exact trip count) + ONE extra prefetch slot
// (depth-2 pipeline: slots A/B live, slot C loaded in-loop). R11's counted loop regressed
// because it rounded stages to multiples of 3 (dead stages); that rounding is gone.
// k_spillfix keeps the uniform flags[2]==0 early-out.

#define CAP 48
#define SPILLCAP 65536

using short8  = __attribute__((ext_vector_type(8))) short;
using float4v = __attribute__((ext_vector_type(4))) float;

static __device__ __forceinline__ float bf2f(unsigned int u16) {
    union { unsigned int i; float f; } v; v.i = u16 << 16; return v.f;
}
static __device__ __forceinline__ float bflo(unsigned int p){
    union { unsigned int i; float f; } v; v.i = p << 16; return v.f;
}
static __device__ __forceinline__ float bfhi(unsigned int p){
    union { unsigned int i; float f; } v; v.i = p & 0xffff0000u; return v.f;
}
static __device__ __forceinline__ unsigned short f2bf(float f) {
    union { float f; unsigned int i; } v; v.f = f;
    unsigned int x = v.i;
    x += 0x7fffu + ((x >> 16) & 1u);   // RNE
    return (unsigned short)(x >> 16);
}
static __device__ __forceinline__ float leaky(float x){ return x > 0.f ? x : 0.2f * x; }

// ---------------- probe dtypes + zero cnt/spillcnt (fused) ----------------
__global__ __launch_bounds__(256) void k_probe_zero(const unsigned int* __restrict__ xw,
                                                    const int* __restrict__ ei,
                                                    int* __restrict__ flags,
                                                    int* __restrict__ cnt, int N) {
    int i = blockIdx.x * 256 + threadIdx.x;
    if (i < N) cnt[i] = 0;
    if (blockIdx.x == 0) {
        __shared__ int insane, oddnz;
        int t = threadIdx.x;
        if (t == 0) { insane = 0; oddnz = 0; }
        __syncthreads();
        unsigned int w = xw[t];
        if (((w >> 7) & 0xFFu) >= 154u) atomicOr(&insane, 1);
        if (ei[2 * t + 1] != 0) atomicOr(&oddnz, 1);
        __syncthreads();
        if (t == 0) { flags[0] = insane ? 1 : 0; flags[1] = oddnz ? 0 : 1; flags[2] = 0; }
    }
}

// ---------------- W -> WT (bf16): WT[l][n][k] = W[l][k][n] ----------------
__global__ __launch_bounds__(256) void k_transpose(const void* __restrict__ W,
                                                   unsigned short* __restrict__ WT,
                                                   const int* __restrict__ flags) {
    int fx = flags[0];
    int idx = blockIdx.x * 256 + threadIdx.x;
    int layer = idx >> 15;
    int rem = idx & 32767;
    int k = rem >> 8, n = rem & 255;
    int srci = layer * 32768 + k * 256 + n;
    unsigned short v;
    if (fx) v = f2bf(((const float*)W)[srci]);
    else    v = ((const unsigned short*)W)[srci];
    WT[layer * 32768 + n * 128 + k] = v;
}

// ---------------- single-pass bucket scatter ----------------
static __device__ __forceinline__ int edge_dst(const int* ei, int E, int i, int is64) {
    return is64 ? ei[2 * E + 2 * i] : ei[E + i];
}
static __device__ __forceinline__ int edge_src(const int* ei, int E, int i, int is64) {
    return is64 ? ei[2 * i] : ei[i];
}

__global__ __launch_bounds__(256) void k_bucket(const int* __restrict__ ei, int E, int N,
                                                int* __restrict__ flags,
                                                int* __restrict__ cnt,
                                                int* __restrict__ bucket,
                                                int* __restrict__ spill) {
    int i = blockIdx.x * 256 + threadIdx.x;
    if (i >= E + N) return;
    int src, dst;
    if (i < E) {
        int is64 = flags[1];
        src = edge_src(ei, E, i, is64);
        dst = edge_dst(ei, E, i, is64);
        if ((unsigned)src >= (unsigned)N) src = 0;
        if ((unsigned)dst >= (unsigned)N) dst = 0;
    } else src = dst = i - E;   // self loop
    int pos = atomicAdd(&cnt[dst], 1);
    if (pos < CAP) {
        bucket[dst * CAP + pos] = src;
    } else {
        int sp = atomicAdd(&flags[2], 1);
        if (sp < SPILLCAP) { spill[2 * sp] = dst; spill[2 * sp + 1] = src; }
    }
}

// ---------------- fused GEMM + alpha (R8-proven) ----------------
__global__ __launch_bounds__(256) void k_gemm_alpha(const void* __restrict__ X,
                                                    const unsigned short* __restrict__ WT,
                                                    const void* __restrict__ atts,
                                                    const void* __restrict__ attd,
                                                    int layer,
                                                    unsigned short* __restrict__ Hb,
                                                    float* __restrict__ as_, float* __restrict__ ad_,
                                                    int N, const int* __restrict__ flags) {
    __shared__ float lds_s[4][16], lds_d[4][16];
    __shared__ unsigned short cbuf[4][16][72];
    int fx = flags[0];
    int mt = blockIdx.x;
    int wave = threadIdx.x >> 6;
    int lane = threadIdx.x & 63;
    int r16 = lane & 15, quad = lane >> 4;
    int m0 = mt << 4;
    int arow = m0 + r16; if (arow >= N) arow = N - 1;
    short8 a[4];
    if (fx) {
        const float* Xf = (const float*)X;
#pragma unroll
        for (int kk = 0; kk < 4; kk++) {
            const float4v* pv = (const float4v*)(Xf + (size_t)arow * 128 + kk * 32 + quad * 8);
            float4v lo = pv[0], hi = pv[1];
            short8 t;
            t[0] = (short)f2bf(lo[0]); t[1] = (short)f2bf(lo[1]);
            t[2] = (short)f2bf(lo[2]); t[3] = (short)f2bf(lo[3]);
            t[4] = (short)f2bf(hi[0]); t[5] = (short)f2bf(hi[1]);
            t[6] = (short)f2bf(hi[2]); t[7] = (short)f2bf(hi[3]);
            a[kk] = t;
        }
    } else {
        const unsigned short* Xh = (const unsigned short*)X;
#pragma unroll
        for (int kk = 0; kk < 4; kk++)
            a[kk] = *(const short8*)(Xh + (size_t)arow * 128 + kk * 32 + quad * 8);
    }
    int head = wave >> 1;
    float ps[4] = {0.f, 0.f, 0.f, 0.f}, pd[4] = {0.f, 0.f, 0.f, 0.f};
#pragma unroll
    for (int nn = 0; nn < 4; nn++) {
        int nt = wave * 4 + nn;
        float4v acc = {0.f, 0.f, 0.f, 0.f};
#pragma unroll
        for (int kk = 0; kk < 4; kk++) {
            short8 b = *(const short8*)(WT + (nt * 16 + r16) * 128 + kk * 32 + quad * 8);
            acc = __builtin_amdgcn_mfma_f32_16x16x32_bf16(a[kk], b, acc, 0, 0, 0);
        }
        int c = (nt * 16 + r16) & 127;
        float sa, da;
        if (fx) {
            sa = ((const float*)atts)[layer * 256 + head * 128 + c];
            da = ((const float*)attd)[layer * 256 + head * 128 + c];
        } else {
            sa = bf2f(((const unsigned short*)atts)[layer * 256 + head * 128 + c]);
            da = bf2f(((const unsigned short*)attd)[layer * 256 + head * 128 + c]);
        }
#pragma unroll
        for (int r = 0; r < 4; r++) {
            cbuf[wave][quad * 4 + r][nn * 16 + r16] = f2bf(acc[r]);   // C/D: col=lane&15, row=quad*4+r [m89]
            ps[r] += acc[r] * sa;
            pd[r] += acc[r] * da;
        }
    }
#pragma unroll
    for (int it = 0; it < 2; it++) {
        int idx = it * 64 + lane;
        int row = idx >> 3, chunk = idx & 7;
        uint4 v = *(const uint4*)&cbuf[wave][row][chunk * 8];
        int grow = m0 + row;
        if (grow < N)
            *(uint4*)(Hb + (size_t)grow * 256 + wave * 64 + chunk * 8) = v;
    }
#pragma unroll
    for (int m = 1; m < 16; m <<= 1) {
#pragma unroll
        for (int r = 0; r < 4; r++) {
            ps[r] += __shfl_xor(ps[r], m);
            pd[r] += __shfl_xor(pd[r], m);
        }
    }
    if (r16 == 0) {
#pragma unroll
        for (int r = 0; r < 4; r++) {
            lds_s[wave][quad * 4 + r] = ps[r];
            lds_d[wave][quad * 4 + r] = pd[r];
        }
    }
    __syncthreads();
    if (threadIdx.x < 16) {
        int row = m0 + threadIdx.x;
        if (row < N) {
            float2 sv = { lds_s[0][threadIdx.x] + lds_s[1][threadIdx.x],
                          lds_s[2][threadIdx.x] + lds_s[3][threadIdx.x] };
            float2 dv = { lds_d[0][threadIdx.x] + lds_d[1][threadIdx.x],
                          lds_d[2][threadIdx.x] + lds_d[3][threadIdx.x] };
            *(float2*)(as_ + 2 * row) = sv;
            *(float2*)(ad_ + 2 * row) = dv;
        }
    }
}

// ---------------- hot aggregate: deg<=CAP only; depth-2 pipelined gather ----------------
static __device__ __forceinline__ void acc8(float* A, float w, uint4 q) {
    A[0] += w * bflo(q.x); A[1] += w * bfhi(q.x);
    A[2] += w * bflo(q.y); A[3] += w * bfhi(q.y);
    A[4] += w * bflo(q.z); A[5] += w * bfhi(q.z);
    A[6] += w * bflo(q.w); A[7] += w * bfhi(q.w);
}

__global__ __launch_bounds__(256) void k_aggregate(const unsigned short* __restrict__ Hb,
                                                   const float* __restrict__ as_, const float* __restrict__ ad_,
                                                   const int* __restrict__ cnt, const int* __restrict__ bucket,
                                                   const void* __restrict__ bias, int layer,
                                                   const int* __restrict__ flags,
                                                   void* __restrict__ outp, int N) {
    int fx = flags[0];
    int n = blockIdx.x * 4 + (threadIdx.x >> 6);
    if (n >= N) return;
    int deg = cnt[n];
    if (deg > CAP) return;           // handled by k_spillfix
    int lane = threadIdx.x & 63;
    int g = lane >> 4;
    int gl = lane & 15;              // owns channels [gl*8, gl*8+8) of each head
    const int* eb = bucket + n * CAP;
    float2 adv = *(const float2*)(ad_ + 2 * n);
    float ad0 = adv.x, ad1 = adv.y;

    // softmax over bucket (single sweep: deg <= 48 <= 64 lanes)
    bool act = lane < deg;
    int s = 0; float l0 = -1e30f, l1 = -1e30f;
    if (act) {
        s = eb[lane]; if ((unsigned)s >= (unsigned)N) s = 0;
        float2 av = *(const float2*)(as_ + 2 * s);
        l0 = leaky(av.x + ad0); l1 = leaky(av.y + ad1);
    }
    float m0 = l0, m1 = l1;
#pragma unroll
    for (int m = 1; m < 64; m <<= 1) { m0 = fmaxf(m0, __shfl_xor(m0, m)); m1 = fmaxf(m1, __shfl_xor(m1, m)); }
    float w0 = act ? __expf(l0 - m0) : 0.f;   // weight==0 for lanes >= deg -> padded slots add exact 0
    float w1 = act ? __expf(l1 - m1) : 0.f;
    float z0 = w0, z1 = w1;
#pragma unroll
    for (int m = 1; m < 64; m <<= 1) { z0 += __shfl_xor(z0, m); z1 += __shfl_xor(z1, m); }

    // Depth-2 pipelined gather, divergent-while (exact trip count = ceil(deg/4) per group).
    // Slot A (q*) is consumed each iteration; slot B (p*) holds group e+4; the loop body
    // issues loads for group e+8 into r* before the FMAs, then rotates A<-B, B<-r.
    float acc0[8] = {0,0,0,0,0,0,0,0}, acc1[8] = {0,0,0,0,0,0,0,0};
    int e = g;
    bool v = e < deg;
    float wq0 = __shfl(w0, e), wq1 = __shfl(w1, e);
    int sq = __shfl(s, e);
    uint4 q0 = {0,0,0,0}, q1 = {0,0,0,0};
    if (v) {
        const unsigned short* row = Hb + ((size_t)sq << 8) + gl * 8;
        q0 = *(const uint4*)row;
        q1 = *(const uint4*)(row + 128);
    }
    int e2 = e + 4;
    bool v2 = e2 < deg;
    float wp0 = __shfl(w0, e2 & 63), wp1 = __shfl(w1, e2 & 63);
    int sp = __shfl(s, e2 & 63);
    uint4 p0 = {0,0,0,0}, p1 = {0,0,0,0};
    if (v2) {
        const unsigned short* row = Hb + ((size_t)sp << 8) + gl * 8;
        p0 = *(const uint4*)row;
        p1 = *(const uint4*)(row + 128);
    }
    while (v) {
        int e3 = e2 + 4;
        bool v3 = e3 < deg;
        float wr0 = __shfl(w0, e3 & 63), wr1 = __shfl(w1, e3 & 63);
        int sr = __shfl(s, e3 & 63);
        uint4 r0 = {0,0,0,0}, r1 = {0,0,0,0};
        if (v3) {
            const unsigned short* row = Hb + ((size_t)sr << 8) + gl * 8;
            r0 = *(const uint4*)row;
            r1 = *(const uint4*)(row + 128);
        }
        acc8(acc0, wq0, q0);
        acc8(acc1, wq1, q1);
        e = e2;  v = v2;  wq0 = wp0; wq1 = wp1; q0 = p0; q1 = p1;
        e2 = e3; v2 = v3; wp0 = wr0; wp1 = wr1; p0 = r0; p1 = r1;
    }

    float inv0 = 1.f / (z0 + 1e-16f), inv1 = 1.f / (z1 + 1e-16f);
#pragma unroll
    for (int k = 0; k < 8; k++) {
        acc0[k] += __shfl_xor(acc0[k], 16); acc0[k] += __shfl_xor(acc0[k], 32);
        acc1[k] += __shfl_xor(acc1[k], 16); acc1[k] += __shfl_xor(acc1[k], 32);
    }

    float vv[8];
    if (fx) {
        const float* bf = (const float*)bias + layer * 128 + gl * 8;
#pragma unroll
        for (int k = 0; k < 8; k++) vv[k] = 0.5f * (acc0[k] * inv0 + acc1[k] * inv1) + bf[k];
    } else {
        const unsigned short* bh = (const unsigned short*)bias + layer * 128 + gl * 8;
        uint4 bv = *(const uint4*)bh;
        float bfv[8] = { bflo(bv.x), bfhi(bv.x), bflo(bv.y), bfhi(bv.y),
                         bflo(bv.z), bfhi(bv.z), bflo(bv.w), bfhi(bv.w) };
#pragma unroll
        for (int k = 0; k < 8; k++) vv[k] = 0.5f * (acc0[k] * inv0 + acc1[k] * inv1) + bfv[k];
    }

    float ss = 0.f;
#pragma unroll
    for (int k = 0; k < 8; k++) ss += vv[k] * vv[k];
#pragma unroll
    for (int m = 1; m < 16; m <<= 1) ss += __shfl_xor(ss, m);
    float inv = 1.f / fmaxf(sqrtf(ss), 1e-12f);

    if (lane < 16) {
        if (fx) {
            float* op = (float*)outp + (size_t)n * 128 + gl * 8;
            float4 o0 = { vv[0] * inv, vv[1] * inv, vv[2] * inv, vv[3] * inv };
            float4 o1 = { vv[4] * inv, vv[5] * inv, vv[6] * inv, vv[7] * inv };
            *(float4*)op = o0;
            *(float4*)(op + 4) = o1;
        } else {
            unsigned short* op = (unsigned short*)outp + (size_t)n * 128 + gl * 8;
            uint4 pk;
            pk.x = (unsigned int)f2bf(vv[0] * inv) | ((unsigned int)f2bf(vv[1] * inv) << 16);
            pk.y = (unsigned int)f2bf(vv[2] * inv) | ((unsigned int)f2bf(vv[3] * inv) << 16);
            pk.z = (unsigned int)f2bf(vv[4] * inv) | ((unsigned int)f2bf(vv[5] * inv) << 16);
            pk.w = (unsigned int)f2bf(vv[6] * inv) | ((unsigned int)f2bf(vv[7] * inv) << 16);
            *(uint4*)op = pk;
        }
    }
}

// ---------------- spill fix: only nodes with deg > CAP (statistically never) ----------------
__global__ __launch_bounds__(256) void k_spillfix(const unsigned short* __restrict__ Hb,
                                                  const float* __restrict__ as_, const float* __restrict__ ad_,
                                                  const int* __restrict__ cnt, const int* __restrict__ bucket,
                                                  const int* __restrict__ spill, const int* __restrict__ flags,
                                                  const void* __restrict__ bias, int layer,
                                                  void* __restrict__ outp, int N) {
    if (flags[2] == 0) return;       // no spills anywhere: hot kernel covered every node
    int fx = flags[0];
    int n = blockIdx.x * 4 + (threadIdx.x >> 6);
    if (n >= N) return;
    int deg = cnt[n];
    if (deg <= CAP) return;          // hot kernel handled it
    int lane = threadIdx.x & 63;
    int g = lane >> 4;
    int gl = lane & 15;
    const int* eb = bucket + n * CAP;
    int sc = flags[2]; if (sc > SPILLCAP) sc = SPILLCAP;
    float2 adv = *(const float2*)(ad_ + 2 * n);
    float ad0 = adv.x, ad1 = adv.y;

    float m0 = -1e30f, m1 = -1e30f;
    for (int i = lane; i < CAP; i += 64) {
        int s = eb[i]; if ((unsigned)s >= (unsigned)N) s = 0;
        float2 av = *(const float2*)(as_ + 2 * s);
        m0 = fmaxf(m0, leaky(av.x + ad0));
        m1 = fmaxf(m1, leaky(av.y + ad1));
    }
    for (int i = lane; i < sc; i += 64) {
        if (spill[2 * i] == n) {
            int s = spill[2 * i + 1]; if ((unsigned)s >= (unsigned)N) s = 0;
            float2 av = *(const float2*)(as_ + 2 * s);
            m0 = fmaxf(m0, leaky(av.x + ad0));
            m1 = fmaxf(m1, leaky(av.y + ad1));
        }
    }
#pragma unroll
    for (int m = 1; m < 64; m <<= 1) { m0 = fmaxf(m0, __shfl_xor(m0, m)); m1 = fmaxf(m1, __shfl_xor(m1, m)); }

    float acc0[8] = {0,0,0,0,0,0,0,0}, acc1[8] = {0,0,0,0,0,0,0,0};
    float z0 = 0.f, z1 = 0.f;
    {
        bool act = lane < CAP;
        int s = 0; float w0 = 0.f, w1 = 0.f;
        if (act) {
            s = eb[lane]; if ((unsigned)s >= (unsigned)N) s = 0;
            float2 av = *(const float2*)(as_ + 2 * s);
            w0 = __expf(leaky(av.x + ad0) - m0);
            w1 = __expf(leaky(av.y + ad1) - m1);
            z0 += w0; z1 += w1;
        }
        for (int j = 0; 4 * j < CAP; j++) {
            int e = 4 * j + g;
            int sq    = __shfl(s, e);
            float wq0 = __shfl(w0, e);
            float wq1 = __shfl(w1, e);
            if (e < CAP) {
                const unsigned short* row = Hb + ((size_t)sq << 8);
                uint4 q0 = *(const uint4*)(row + gl * 8);
                uint4 q1 = *(const uint4*)(row + 128 + gl * 8);
                acc8(acc0, wq0, q0);
                acc8(acc1, wq1, q1);
            }
        }
    }
    for (int i = 0; i < sc; i++) {
        int d = spill[2 * i];
        if (d != n) continue;
        int s = spill[2 * i + 1]; if ((unsigned)s >= (unsigned)N) s = 0;
        float2 av = *(const float2*)(as_ + 2 * s);
        float w0 = __expf(leaky(av.x + ad0) - m0);
        float w1 = __expf(leaky(av.y + ad1) - m1);
        if (lane == 0) { z0 += w0; z1 += w1; }
        if (g == 0) {
            const unsigned short* row = Hb + ((size_t)s << 8);
            uint4 q0 = *(const uint4*)(row + gl * 8);
            uint4 q1 = *(const uint4*)(row + 128 + gl * 8);
            acc8(acc0, w0, q0);
            acc8(acc1, w1, q1);
        }
    }
#pragma unroll
    for (int m = 1; m < 64; m <<= 1) { z0 += __shfl_xor(z0, m); z1 += __shfl_xor(z1, m); }

    float inv0 = 1.f / (z0 + 1e-16f), inv1 = 1.f / (z1 + 1e-16f);
#pragma unroll
    for (int k = 0; k < 8; k++) {
        acc0[k] += __shfl_xor(acc0[k], 16); acc0[k] += __shfl_xor(acc0[k], 32);
        acc1[k] += __shfl_xor(acc1[k], 16); acc1[k] += __shfl_xor(acc1[k], 32);
    }
    float vv[8];
    if (fx) {
        const float* bf = (const float*)bias + layer * 128 + gl * 8;
#pragma unroll
        for (int k = 0; k < 8; k++) vv[k] = 0.5f * (acc0[k] * inv0 + acc1[k] * inv1) + bf[k];
    } else {
        const unsigned short* bh = (const unsigned short*)bias + layer * 128 + gl * 8;
        uint4 bv = *(const uint4*)bh;
        float bfv[8] = { bflo(bv.x), bfhi(bv.x), bflo(bv.y), bfhi(bv.y),
                         bflo(bv.z), bfhi(bv.z), bflo(bv.w), bfhi(bv.w) };
#pragma unroll
        for (int k = 0; k < 8; k++) vv[k] = 0.5f * (acc0[k] * inv0 + acc1[k] * inv1) + bfv[k];
    }
    float ss = 0.f;
#pragma unroll
    for (int k = 0; k < 8; k++) ss += vv[k] * vv[k];
#pragma unroll
    for (int m = 1; m < 16; m <<= 1) ss += __shfl_xor(ss, m);
    float inv = 1.f / fmaxf(sqrtf(ss), 1e-12f);
    if (lane < 16) {
        if (fx) {
            float* op = (float*)outp + (size_t)n * 128 + gl * 8;
            float4 o0 = { vv[0] * inv, vv[1] * inv, vv[2] * inv, vv[3] * inv };
            float4 o1 = { vv[4] * inv, vv[5] * inv, vv[6] * inv, vv[7] * inv };
            *(float4*)op = o0;
            *(float4*)(op + 4) = o1;
        } else {
            unsigned short* op = (unsigned short*)outp + (size_t)n * 128 + gl * 8;
            uint4 pk;
            pk.x = (unsigned int)f2bf(vv[0] * inv) | ((unsigned int)f2bf(vv[1] * inv) << 16);
            pk.y = (unsigned int)f2bf(vv[2] * inv) | ((unsigned int)f2bf(vv[3] * inv) << 16);
            pk.z = (unsigned int)f2bf(vv[4] * inv) | ((unsigned int)f2bf(vv[5] * inv) << 16);
            pk.w = (unsigned int)f2bf(vv[6] * inv) | ((unsigned int)f2bf(vv[7] * inv) << 16);
            *(uint4*)op = pk;
        }
    }
}

extern "C" void kernel_launch(void* const* d_in, const int* in_sizes, int n_in,
                              void* d_out, int out_size, void* d_ws, size_t ws_size,
                              hipStream_t stream) {
    const void* x    = d_in[0];
    const int*  ei   = (const int*)d_in[1];
    const void* W    = d_in[2];
    const void* atts = d_in[3];
    const void* attd = d_in[4];
    const void* bias = d_in[5];

    int N = in_sizes[0] / 128;
    int E = in_sizes[1] / 2;

    char* p = (char*)d_ws;
    auto alloc = [&](size_t bytes) -> char* {
        char* q = p; p += (bytes + 255) & ~(size_t)255; return q;
    };
    int* flags   = (int*)alloc(256);                                   // [0]=fx [1]=is64 [2]=spillcnt
    int* cnt     = (int*)alloc((size_t)N * 4);
    float* as_   = (float*)alloc((size_t)N * 2 * 4);
    float* ad_   = (float*)alloc((size_t)N * 2 * 4);
    unsigned short* wt = (unsigned short*)alloc(2 * 256 * 128 * 2);
    int* spill   = (int*)alloc((size_t)SPILLCAP * 2 * 4);              // 512 KB
    int* bucket  = (int*)alloc((size_t)N * CAP * 4);                   // 9.6 MB
    unsigned short* hbuf = (unsigned short*)alloc((size_t)N * 256 * 2);// 25.6 MB
    // total ~36.9 MB

    k_probe_zero<<<(N + 255) / 256, 256, 0, stream>>>((const unsigned int*)x, ei, flags, cnt, N);
    k_bucket<<<(E + N + 255) / 256, 256, 0, stream>>>(ei, E, N, flags, cnt, bucket, spill);
    k_transpose<<<256, 256, 0, stream>>>(W, wt, flags);

    int mtiles = (N + 15) / 16;
    int ngrp = (N + 3) / 4;
    for (int l = 0; l < 2; l++) {
        const void* xin = (l == 0) ? x : (const void*)d_out;
        k_gemm_alpha<<<mtiles, 256, 0, stream>>>(xin, wt + l * 32768, atts, attd, l,
                                                 hbuf, as_, ad_, N, flags);
        k_aggregate<<<ngrp, 256, 0, stream>>>(hbuf, as_, ad_, cnt, bucket,
                                              bias, l, flags, d_out, N);
        k_spillfix<<<ngrp, 256, 0, stream>>>(hbuf, as_, ad_, cnt, bucket, spill, flags,
                                             bias, l, d_out, N);
    }
}

// Round 4
// 343.657 us; speedup vs baseline: 1.0600x; 1.0393x over previous
//
#include <hip/hip_runtime.h>

// GAT, 2 layers, H=2 heads, D=C=128, concat=False (head mean), L2 normalize after each layer.
// Float tensors: fp32 OR bf16 (runtime-probed). edge_index: int32 OR int64 (runtime-probed).
// Internal h-matrix bf16 row-major [N][256].
// R14: gather loop reverted to EXACT R10 form (single prefetch slot; R11/R12 pipelining both
// regressed). New: softmax max-reduce skipped (overflow-guarded by __any(l>30) fallback) and
// z sum-reduce deferred to after the gather loop -> pre-gather serial chain halved, 24 fewer
// ds_bpermute per node. k_transpose merged into k_bucket (one fewer dispatch).

#define CAP 48
#define SPILLCAP 65536

using short8  = __attribute__((ext_vector_type(8))) short;
using float4v = __attribute__((ext_vector_type(4))) float;

static __device__ __forceinline__ float bf2f(unsigned int u16) {
    union { unsigned int i; float f; } v; v.i = u16 << 16; return v.f;
}
static __device__ __forceinline__ float bflo(unsigned int p){
    union { unsigned int i; float f; } v; v.i = p << 16; return v.f;
}
static __device__ __forceinline__ float bfhi(unsigned int p){
    union { unsigned int i; float f; } v; v.i = p & 0xffff0000u; return v.f;
}
static __device__ __forceinline__ unsigned short f2bf(float f) {
    union { float f; unsigned int i; } v; v.f = f;
    unsigned int x = v.i;
    x += 0x7fffu + ((x >> 16) & 1u);   // RNE
    return (unsigned short)(x >> 16);
}
static __device__ __forceinline__ float leaky(float x){ return x > 0.f ? x : 0.2f * x; }

// ---------------- probe dtypes + zero cnt/spillcnt (fused) ----------------
__global__ __launch_bounds__(256) void k_probe_zero(const unsigned int* __restrict__ xw,
                                                    const int* __restrict__ ei,
                                                    int* __restrict__ flags,
                                                    int* __restrict__ cnt, int N) {
    int i = blockIdx.x * 256 + threadIdx.x;
    if (i < N) cnt[i] = 0;
    if (blockIdx.x == 0) {
        __shared__ int insane, oddnz;
        int t = threadIdx.x;
        if (t == 0) { insane = 0; oddnz = 0; }
        __syncthreads();
        unsigned int w = xw[t];
        if (((w >> 7) & 0xFFu) >= 154u) atomicOr(&insane, 1);
        if (ei[2 * t + 1] != 0) atomicOr(&oddnz, 1);
        __syncthreads();
        if (t == 0) { flags[0] = insane ? 1 : 0; flags[1] = oddnz ? 0 : 1; flags[2] = 0; }
    }
}

// ---------------- single-pass bucket scatter + W->WT transpose (fused) ----------------
static __device__ __forceinline__ int edge_dst(const int* ei, int E, int i, int is64) {
    return is64 ? ei[2 * E + 2 * i] : ei[E + i];
}
static __device__ __forceinline__ int edge_src(const int* ei, int E, int i, int is64) {
    return is64 ? ei[2 * i] : ei[i];
}

__global__ __launch_bounds__(256) void k_bucket(const int* __restrict__ ei, int E, int N,
                                                int* __restrict__ flags,
                                                int* __restrict__ cnt,
                                                int* __restrict__ bucket,
                                                int* __restrict__ spill,
                                                const void* __restrict__ W,
                                                unsigned short* __restrict__ WT) {
    int i = blockIdx.x * 256 + threadIdx.x;
    if (i < 65536) {
        // transpose: WT[l][n][k] = W[l][k][n]  (2 layers x 128 x 256)
        int fx = flags[0];
        int layer = i >> 15;
        int rem = i & 32767;
        int k = rem >> 8, n = rem & 255;
        int srci = layer * 32768 + k * 256 + n;
        unsigned short v;
        if (fx) v = f2bf(((const float*)W)[srci]);
        else    v = ((const unsigned short*)W)[srci];
        WT[layer * 32768 + n * 128 + k] = v;
    }
    if (i >= E + N) return;
    int src, dst;
    if (i < E) {
        int is64 = flags[1];
        src = edge_src(ei, E, i, is64);
        dst = edge_dst(ei, E, i, is64);
        if ((unsigned)src >= (unsigned)N) src = 0;
        if ((unsigned)dst >= (unsigned)N) dst = 0;
    } else src = dst = i - E;   // self loop
    int pos = atomicAdd(&cnt[dst], 1);
    if (pos < CAP) {
        bucket[dst * CAP + pos] = src;
    } else {
        int sp = atomicAdd(&flags[2], 1);
        if (sp < SPILLCAP) { spill[2 * sp] = dst; spill[2 * sp + 1] = src; }
    }
}

// ---------------- fused GEMM + alpha (R8-proven) ----------------
__global__ __launch_bounds__(256) void k_gemm_alpha(const void* __restrict__ X,
                                                    const unsigned short* __restrict__ WT,
                                                    const void* __restrict__ atts,
                                                    const void* __restrict__ attd,
                                                    int layer,
                                                    unsigned short* __restrict__ Hb,
                                                    float* __restrict__ as_, float* __restrict__ ad_,
                                                    int N, const int* __restrict__ flags) {
    __shared__ float lds_s[4][16], lds_d[4][16];
    __shared__ unsigned short cbuf[4][16][72];
    int fx = flags[0];
    int mt = blockIdx.x;
    int wave = threadIdx.x >> 6;
    int lane = threadIdx.x & 63;
    int r16 = lane & 15, quad = lane >> 4;
    int m0 = mt << 4;
    int arow = m0 + r16; if (arow >= N) arow = N - 1;
    short8 a[4];
    if (fx) {
        const float* Xf = (const float*)X;
#pragma unroll
        for (int kk = 0; kk < 4; kk++) {
            const float4v* pv = (const float4v*)(Xf + (size_t)arow * 128 + kk * 32 + quad * 8);
            float4v lo = pv[0], hi = pv[1];
            short8 t;
            t[0] = (short)f2bf(lo[0]); t[1] = (short)f2bf(lo[1]);
            t[2] = (short)f2bf(lo[2]); t[3] = (short)f2bf(lo[3]);
            t[4] = (short)f2bf(hi[0]); t[5] = (short)f2bf(hi[1]);
            t[6] = (short)f2bf(hi[2]); t[7] = (short)f2bf(hi[3]);
            a[kk] = t;
        }
    } else {
        const unsigned short* Xh = (const unsigned short*)X;
#pragma unroll
        for (int kk = 0; kk < 4; kk++)
            a[kk] = *(const short8*)(Xh + (size_t)arow * 128 + kk * 32 + quad * 8);
    }
    int head = wave >> 1;
    float ps[4] = {0.f, 0.f, 0.f, 0.f}, pd[4] = {0.f, 0.f, 0.f, 0.f};
#pragma unroll
    for (int nn = 0; nn < 4; nn++) {
        int nt = wave * 4 + nn;
        float4v acc = {0.f, 0.f, 0.f, 0.f};
#pragma unroll
        for (int kk = 0; kk < 4; kk++) {
            short8 b = *(const short8*)(WT + (nt * 16 + r16) * 128 + kk * 32 + quad * 8);
            acc = __builtin_amdgcn_mfma_f32_16x16x32_bf16(a[kk], b, acc, 0, 0, 0);
        }
        int c = (nt * 16 + r16) & 127;
        float sa, da;
        if (fx) {
            sa = ((const float*)atts)[layer * 256 + head * 128 + c];
            da = ((const float*)attd)[layer * 256 + head * 128 + c];
        } else {
            sa = bf2f(((const unsigned short*)atts)[layer * 256 + head * 128 + c]);
            da = bf2f(((const unsigned short*)attd)[layer * 256 + head * 128 + c]);
        }
#pragma unroll
        for (int r = 0; r < 4; r++) {
            cbuf[wave][quad * 4 + r][nn * 16 + r16] = f2bf(acc[r]);   // C/D: col=lane&15, row=quad*4+r [m89]
            ps[r] += acc[r] * sa;
            pd[r] += acc[r] * da;
        }
    }
#pragma unroll
    for (int it = 0; it < 2; it++) {
        int idx = it * 64 + lane;
        int row = idx >> 3, chunk = idx & 7;
        uint4 v = *(const uint4*)&cbuf[wave][row][chunk * 8];
        int grow = m0 + row;
        if (grow < N)
            *(uint4*)(Hb + (size_t)grow * 256 + wave * 64 + chunk * 8) = v;
    }
#pragma unroll
    for (int m = 1; m < 16; m <<= 1) {
#pragma unroll
        for (int r = 0; r < 4; r++) {
            ps[r] += __shfl_xor(ps[r], m);
            pd[r] += __shfl_xor(pd[r], m);
        }
    }
    if (r16 == 0) {
#pragma unroll
        for (int r = 0; r < 4; r++) {
            lds_s[wave][quad * 4 + r] = ps[r];
            lds_d[wave][quad * 4 + r] = pd[r];
        }
    }
    __syncthreads();
    if (threadIdx.x < 16) {
        int row = m0 + threadIdx.x;
        if (row < N) {
            float2 sv = { lds_s[0][threadIdx.x] + lds_s[1][threadIdx.x],
                          lds_s[2][threadIdx.x] + lds_s[3][threadIdx.x] };
            float2 dv = { lds_d[0][threadIdx.x] + lds_d[1][threadIdx.x],
                          lds_d[2][threadIdx.x] + lds_d[3][threadIdx.x] };
            *(float2*)(as_ + 2 * row) = sv;
            *(float2*)(ad_ + 2 * row) = dv;
        }
    }
}

// ---------------- hot aggregate: deg<=CAP only; R10 gather; trimmed preamble ----------------
static __device__ __forceinline__ void acc8(float* A, float w, uint4 q) {
    A[0] += w * bflo(q.x); A[1] += w * bfhi(q.x);
    A[2] += w * bflo(q.y); A[3] += w * bfhi(q.y);
    A[4] += w * bflo(q.z); A[5] += w * bfhi(q.z);
    A[6] += w * bflo(q.w); A[7] += w * bfhi(q.w);
}

__global__ __launch_bounds__(256) void k_aggregate(const unsigned short* __restrict__ Hb,
                                                   const float* __restrict__ as_, const float* __restrict__ ad_,
                                                   const int* __restrict__ cnt, const int* __restrict__ bucket,
                                                   const void* __restrict__ bias, int layer,
                                                   const int* __restrict__ flags,
                                                   void* __restrict__ outp, int N) {
    int fx = flags[0];
    int n = blockIdx.x * 4 + (threadIdx.x >> 6);
    if (n >= N) return;
    int deg = cnt[n];
    if (deg > CAP) return;           // handled by k_spillfix
    int lane = threadIdx.x & 63;
    int g = lane >> 4;
    int gl = lane & 15;              // owns channels [gl*8, gl*8+8) of each head
    const int* eb = bucket + n * CAP;
    float2 adv = *(const float2*)(ad_ + 2 * n);
    float ad0 = adv.x, ad1 = adv.y;

    // logits (single sweep: deg <= 48 <= 64 lanes)
    bool act = lane < deg;
    int s = 0; float l0 = -1e30f, l1 = -1e30f;
    if (act) {
        s = eb[lane]; if ((unsigned)s >= (unsigned)N) s = 0;
        float2 av = *(const float2*)(as_ + 2 * s);
        l0 = leaky(av.x + ad0); l1 = leaky(av.y + ad1);
    }
    // max-sub is mathematically redundant (alpha = exp(l)/sum exp(l)); skip the 12-bpermute
    // max reduction unless logits are large enough to overflow exp (never for sane inputs).
    float m0 = 0.f, m1 = 0.f;
    if (__any(fmaxf(l0, l1) > 30.f)) {
        m0 = l0; m1 = l1;
#pragma unroll
        for (int m = 1; m < 64; m <<= 1) { m0 = fmaxf(m0, __shfl_xor(m0, m)); m1 = fmaxf(m1, __shfl_xor(m1, m)); }
    }
    float w0 = act ? __expf(l0 - m0) : 0.f;   // weight==0 for lanes >= deg
    float w1 = act ? __expf(l1 - m1) : 0.f;
    // z sum-reduce DEFERRED to after the gather loop (only needed in epilogue)

    // R10 gather: single prefetch slot, divergent-while, exact trip count
    float acc0[8] = {0,0,0,0,0,0,0,0}, acc1[8] = {0,0,0,0,0,0,0,0};
    int e = g;
    bool v = e < deg;
    float wq0 = __shfl(w0, e), wq1 = __shfl(w1, e);
    int sq = __shfl(s, e);
    uint4 q0, q1;
    if (v) {
        const unsigned short* row = Hb + ((size_t)sq << 8);
        q0 = *(const uint4*)(row + gl * 8);
        q1 = *(const uint4*)(row + 128 + gl * 8);
    }
    while (v) {
        int en = e + 4;
        bool vn = en < deg;
        float wn0 = __shfl(w0, en & 63), wn1 = __shfl(w1, en & 63);
        int sn = __shfl(s, en & 63);
        uint4 p0, p1;
        if (vn) {
            const unsigned short* row = Hb + ((size_t)sn << 8);
            p0 = *(const uint4*)(row + gl * 8);
            p1 = *(const uint4*)(row + 128 + gl * 8);
        }
        acc8(acc0, wq0, q0);
        acc8(acc1, wq1, q1);
        e = en; v = vn; wq0 = wn0; wq1 = wn1; q0 = p0; q1 = p1;
    }

    // deferred softmax denominator
    float z0 = w0, z1 = w1;
#pragma unroll
    for (int m = 1; m < 64; m <<= 1) { z0 += __shfl_xor(z0, m); z1 += __shfl_xor(z1, m); }
    float inv0 = 1.f / (z0 + 1e-16f), inv1 = 1.f / (z1 + 1e-16f);
#pragma unroll
    for (int k = 0; k < 8; k++) {
        acc0[k] += __shfl_xor(acc0[k], 16); acc0[k] += __shfl_xor(acc0[k], 32);
        acc1[k] += __shfl_xor(acc1[k], 16); acc1[k] += __shfl_xor(acc1[k], 32);
    }

    float vv[8];
    if (fx) {
        const float* bf = (const float*)bias + layer * 128 + gl * 8;
#pragma unroll
        for (int k = 0; k < 8; k++) vv[k] = 0.5f * (acc0[k] * inv0 + acc1[k] * inv1) + bf[k];
    } else {
        const unsigned short* bh = (const unsigned short*)bias + layer * 128 + gl * 8;
        uint4 bv = *(const uint4*)bh;
        float bfv[8] = { bflo(bv.x), bfhi(bv.x), bflo(bv.y), bfhi(bv.y),
                         bflo(bv.z), bfhi(bv.z), bflo(bv.w), bfhi(bv.w) };
#pragma unroll
        for (int k = 0; k < 8; k++) vv[k] = 0.5f * (acc0[k] * inv0 + acc1[k] * inv1) + bfv[k];
    }

    float ss = 0.f;
#pragma unroll
    for (int k = 0; k < 8; k++) ss += vv[k] * vv[k];
#pragma unroll
    for (int m = 1; m < 16; m <<= 1) ss += __shfl_xor(ss, m);
    float inv = 1.f / fmaxf(sqrtf(ss), 1e-12f);

    if (lane < 16) {
        if (fx) {
            float* op = (float*)outp + (size_t)n * 128 + gl * 8;
            float4 o0 = { vv[0] * inv, vv[1] * inv, vv[2] * inv, vv[3] * inv };
            float4 o1 = { vv[4] * inv, vv[5] * inv, vv[6] * inv, vv[7] * inv };
            *(float4*)op = o0;
            *(float4*)(op + 4) = o1;
        } else {
            unsigned short* op = (unsigned short*)outp + (size_t)n * 128 + gl * 8;
            uint4 pk;
            pk.x = (unsigned int)f2bf(vv[0] * inv) | ((unsigned int)f2bf(vv[1] * inv) << 16);
            pk.y = (unsigned int)f2bf(vv[2] * inv) | ((unsigned int)f2bf(vv[3] * inv) << 16);
            pk.z = (unsigned int)f2bf(vv[4] * inv) | ((unsigned int)f2bf(vv[5] * inv) << 16);
            pk.w = (unsigned int)f2bf(vv[6] * inv) | ((unsigned int)f2bf(vv[7] * inv) << 16);
            *(uint4*)op = pk;
        }
    }
}

// ---------------- spill fix: only nodes with deg > CAP (statistically never) ----------------
__global__ __launch_bounds__(256) void k_spillfix(const unsigned short* __restrict__ Hb,
                                                  const float* __restrict__ as_, const float* __restrict__ ad_,
                                                  const int* __restrict__ cnt, const int* __restrict__ bucket,
                                                  const int* __restrict__ spill, const int* __restrict__ flags,
                                                  const void* __restrict__ bias, int layer,
                                                  void* __restrict__ outp, int N) {
    if (flags[2] == 0) return;       // no spills anywhere: hot kernel covered every node
    int fx = flags[0];
    int n = blockIdx.x * 4 + (threadIdx.x >> 6);
    if (n >= N) return;
    int deg = cnt[n];
    if (deg <= CAP) return;          // hot kernel handled it
    int lane = threadIdx.x & 63;
    int g = lane >> 4;
    int gl = lane & 15;
    const int* eb = bucket + n * CAP;
    int sc = flags[2]; if (sc > SPILLCAP) sc = SPILLCAP;
    float2 adv = *(const float2*)(ad_ + 2 * n);
    float ad0 = adv.x, ad1 = adv.y;

    float m0 = -1e30f, m1 = -1e30f;
    for (int i = lane; i < CAP; i += 64) {
        int s = eb[i]; if ((unsigned)s >= (unsigned)N) s = 0;
        float2 av = *(const float2*)(as_ + 2 * s);
        m0 = fmaxf(m0, leaky(av.x + ad0));
        m1 = fmaxf(m1, leaky(av.y + ad1));
    }
    for (int i = lane; i < sc; i += 64) {
        if (spill[2 * i] == n) {
            int s = spill[2 * i + 1]; if ((unsigned)s >= (unsigned)N) s = 0;
            float2 av = *(const float2*)(as_ + 2 * s);
            m0 = fmaxf(m0, leaky(av.x + ad0));
            m1 = fmaxf(m1, leaky(av.y + ad1));
        }
    }
#pragma unroll
    for (int m = 1; m < 64; m <<= 1) { m0 = fmaxf(m0, __shfl_xor(m0, m)); m1 = fmaxf(m1, __shfl_xor(m1, m)); }

    float acc0[8] = {0,0,0,0,0,0,0,0}, acc1[8] = {0,0,0,0,0,0,0,0};
    float z0 = 0.f, z1 = 0.f;
    {
        bool act = lane < CAP;
        int s = 0; float w0 = 0.f, w1 = 0.f;
        if (act) {
            s = eb[lane]; if ((unsigned)s >= (unsigned)N) s = 0;
            float2 av = *(const float2*)(as_ + 2 * s);
            w0 = __expf(leaky(av.x + ad0) - m0);
            w1 = __expf(leaky(av.y + ad1) - m1);
            z0 += w0; z1 += w1;
        }
        for (int j = 0; 4 * j < CAP; j++) {
            int e = 4 * j + g;
            int sq    = __shfl(s, e);
            float wq0 = __shfl(w0, e);
            float wq1 = __shfl(w1, e);
            if (e < CAP) {
                const unsigned short* row = Hb + ((size_t)sq << 8);
                uint4 q0 = *(const uint4*)(row + gl * 8);
                uint4 q1 = *(const uint4*)(row + 128 + gl * 8);
                acc8(acc0, wq0, q0);
                acc8(acc1, wq1, q1);
            }
        }
    }
    for (int i = 0; i < sc; i++) {
        int d = spill[2 * i];
        if (d != n) continue;
        int s = spill[2 * i + 1]; if ((unsigned)s >= (unsigned)N) s = 0;
        float2 av = *(const float2*)(as_ + 2 * s);
        float w0 = __expf(leaky(av.x + ad0) - m0);
        float w1 = __expf(leaky(av.y + ad1) - m1);
        if (lane == 0) { z0 += w0; z1 += w1; }
        if (g == 0) {
            const unsigned short* row = Hb + ((size_t)s << 8);
            uint4 q0 = *(const uint4*)(row + gl * 8);
            uint4 q1 = *(const uint4*)(row + 128 + gl * 8);
            acc8(acc0, w0, q0);
            acc8(acc1, w1, q1);
        }
    }
#pragma unroll
    for (int m = 1; m < 64; m <<= 1) { z0 += __shfl_xor(z0, m); z1 += __shfl_xor(z1, m); }

    float inv0 = 1.f / (z0 + 1e-16f), inv1 = 1.f / (z1 + 1e-16f);
#pragma unroll
    for (int k = 0; k < 8; k++) {
        acc0[k] += __shfl_xor(acc0[k], 16); acc0[k] += __shfl_xor(acc0[k], 32);
        acc1[k] += __shfl_xor(acc1[k], 16); acc1[k] += __shfl_xor(acc1[k], 32);
    }
    float vv[8];
    if (fx) {
        const float* bf = (const float*)bias + layer * 128 + gl * 8;
#pragma unroll
        for (int k = 0; k < 8; k++) vv[k] = 0.5f * (acc0[k] * inv0 + acc1[k] * inv1) + bf[k];
    } else {
        const unsigned short* bh = (const unsigned short*)bias + layer * 128 + gl * 8;
        uint4 bv = *(const uint4*)bh;
        float bfv[8] = { bflo(bv.x), bfhi(bv.x), bflo(bv.y), bfhi(bv.y),
                         bflo(bv.z), bfhi(bv.z), bflo(bv.w), bfhi(bv.w) };
#pragma unroll
        for (int k = 0; k < 8; k++) vv[k] = 0.5f * (acc0[k] * inv0 + acc1[k] * inv1) + bfv[k];
    }
    float ss = 0.f;
#pragma unroll
    for (int k = 0; k < 8; k++) ss += vv[k] * vv[k];
#pragma unroll
    for (int m = 1; m < 16; m <<= 1) ss += __shfl_xor(ss, m);
    float inv = 1.f / fmaxf(sqrtf(ss), 1e-12f);
    if (lane < 16) {
        if (fx) {
            float* op = (float*)outp + (size_t)n * 128 + gl * 8;
            float4 o0 = { vv[0] * inv, vv[1] * inv, vv[2] * inv, vv[3] * inv };
            float4 o1 = { vv[4] * inv, vv[5] * inv, vv[6] * inv, vv[7] * inv };
            *(float4*)op = o0;
            *(float4*)(op + 4) = o1;
        } else {
            unsigned short* op = (unsigned short*)outp + (size_t)n * 128 + gl * 8;
            uint4 pk;
            pk.x = (unsigned int)f2bf(vv[0] * inv) | ((unsigned int)f2bf(vv[1] * inv) << 16);
            pk.y = (unsigned int)f2bf(vv[2] * inv) | ((unsigned int)f2bf(vv[3] * inv) << 16);
            pk.z = (unsigned int)f2bf(vv[4] * inv) | ((unsigned int)f2bf(vv[5] * inv) << 16);
            pk.w = (unsigned int)f2bf(vv[6] * inv) | ((unsigned int)f2bf(vv[7] * inv) << 16);
            *(uint4*)op = pk;
        }
    }
}

extern "C" void kernel_launch(void* const* d_in, const int* in_sizes, int n_in,
                              void* d_out, int out_size, void* d_ws, size_t ws_size,
                              hipStream_t stream) {
    const void* x    = d_in[0];
    const int*  ei   = (const int*)d_in[1];
    const void* W    = d_in[2];
    const void* atts = d_in[3];
    const void* attd = d_in[4];
    const void* bias = d_in[5];

    int N = in_sizes[0] / 128;
    int E = in_sizes[1] / 2;

    char* p = (char*)d_ws;
    auto alloc = [&](size_t bytes) -> char* {
        char* q = p; p += (bytes + 255) & ~(size_t)255; return q;
    };
    int* flags   = (int*)alloc(256);                                   // [0]=fx [1]=is64 [2]=spillcnt
    int* cnt     = (int*)alloc((size_t)N * 4);
    float* as_   = (float*)alloc((size_t)N * 2 * 4);
    float* ad_   = (float*)alloc((size_t)N * 2 * 4);
    unsigned short* wt = (unsigned short*)alloc(2 * 256 * 128 * 2);
    int* spill   = (int*)alloc((size_t)SPILLCAP * 2 * 4);              // 512 KB
    int* bucket  = (int*)alloc((size_t)N * CAP * 4);                   // 9.6 MB
    unsigned short* hbuf = (unsigned short*)alloc((size_t)N * 256 * 2);// 25.6 MB
    // total ~36.9 MB

    k_probe_zero<<<(N + 255) / 256, 256, 0, stream>>>((const unsigned int*)x, ei, flags, cnt, N);
    k_bucket<<<(E + N + 255) / 256, 256, 0, stream>>>(ei, E, N, flags, cnt, bucket, spill, W, wt);

    int mtiles = (N + 15) / 16;
    int ngrp = (N + 3) / 4;
    for (int l = 0; l < 2; l++) {
        const void* xin = (l == 0) ? x : (const void*)d_out;
        k_gemm_alpha<<<mtiles, 256, 0, stream>>>(xin, wt + l * 32768, atts, attd, l,
                                                 hbuf, as_, ad_, N, flags);
        k_aggregate<<<ngrp, 256, 0, stream>>>(hbuf, as_, ad_, cnt, bucket,
                                              bias, l, flags, d_out, N);
        k_spillfix<<<ngrp, 256, 0, stream>>>(hbuf, as_, ad_, cnt, bucket, spill, flags,
                                             bias, l, d_out, N);
    }
}

// Round 5
// 332.019 us; speedup vs baseline: 1.0971x; 1.0351x over previous
//
#include <hip/hip_runtime.h>

// GAT, 2 layers, H=2 heads, D=C=128, concat=False (head mean), L2 normalize after each layer.
// Float tensors: fp32 OR bf16 (runtime-probed). edge_index: int32 OR int64 (runtime-probed).
// Internal h-matrix bf16 row-major [N][256].
// R15: k_gemm_alpha widened to 32 rows/block (2 m-tiles). Loop nn->kk->mi reuses each
// B-fragment for 2 MFMA (halves B-load:MFMA ratio, halves block count + WT re-reads).
// k_aggregate unchanged from R14 (isolates the gemm delta).

#define CAP 48
#define SPILLCAP 65536

using short8  = __attribute__((ext_vector_type(8))) short;
using float4v = __attribute__((ext_vector_type(4))) float;

static __device__ __forceinline__ float bf2f(unsigned int u16) {
    union { unsigned int i; float f; } v; v.i = u16 << 16; return v.f;
}
static __device__ __forceinline__ float bflo(unsigned int p){
    union { unsigned int i; float f; } v; v.i = p << 16; return v.f;
}
static __device__ __forceinline__ float bfhi(unsigned int p){
    union { unsigned int i; float f; } v; v.i = p & 0xffff0000u; return v.f;
}
static __device__ __forceinline__ unsigned short f2bf(float f) {
    union { float f; unsigned int i; } v; v.f = f;
    unsigned int x = v.i;
    x += 0x7fffu + ((x >> 16) & 1u);   // RNE
    return (unsigned short)(x >> 16);
}
static __device__ __forceinline__ float leaky(float x){ return x > 0.f ? x : 0.2f * x; }

// ---------------- probe dtypes + zero cnt/spillcnt (fused) ----------------
__global__ __launch_bounds__(256) void k_probe_zero(const unsigned int* __restrict__ xw,
                                                    const int* __restrict__ ei,
                                                    int* __restrict__ flags,
                                                    int* __restrict__ cnt, int N) {
    int i = blockIdx.x * 256 + threadIdx.x;
    if (i < N) cnt[i] = 0;
    if (blockIdx.x == 0) {
        __shared__ int insane, oddnz;
        int t = threadIdx.x;
        if (t == 0) { insane = 0; oddnz = 0; }
        __syncthreads();
        unsigned int w = xw[t];
        if (((w >> 7) & 0xFFu) >= 154u) atomicOr(&insane, 1);
        if (ei[2 * t + 1] != 0) atomicOr(&oddnz, 1);
        __syncthreads();
        if (t == 0) { flags[0] = insane ? 1 : 0; flags[1] = oddnz ? 0 : 1; flags[2] = 0; }
    }
}

// ---------------- single-pass bucket scatter + W->WT transpose (fused) ----------------
static __device__ __forceinline__ int edge_dst(const int* ei, int E, int i, int is64) {
    return is64 ? ei[2 * E + 2 * i] : ei[E + i];
}
static __device__ __forceinline__ int edge_src(const int* ei, int E, int i, int is64) {
    return is64 ? ei[2 * i] : ei[i];
}

__global__ __launch_bounds__(256) void k_bucket(const int* __restrict__ ei, int E, int N,
                                                int* __restrict__ flags,
                                                int* __restrict__ cnt,
                                                int* __restrict__ bucket,
                                                int* __restrict__ spill,
                                                const void* __restrict__ W,
                                                unsigned short* __restrict__ WT) {
    int i = blockIdx.x * 256 + threadIdx.x;
    if (i < 65536) {
        // transpose: WT[l][n][k] = W[l][k][n]  (2 layers x 128 x 256)
        int fx = flags[0];
        int layer = i >> 15;
        int rem = i & 32767;
        int k = rem >> 8, n = rem & 255;
        int srci = layer * 32768 + k * 256 + n;
        unsigned short v;
        if (fx) v = f2bf(((const float*)W)[srci]);
        else    v = ((const unsigned short*)W)[srci];
        WT[layer * 32768 + n * 128 + k] = v;
    }
    if (i >= E + N) return;
    int src, dst;
    if (i < E) {
        int is64 = flags[1];
        src = edge_src(ei, E, i, is64);
        dst = edge_dst(ei, E, i, is64);
        if ((unsigned)src >= (unsigned)N) src = 0;
        if ((unsigned)dst >= (unsigned)N) dst = 0;
    } else src = dst = i - E;   // self loop
    int pos = atomicAdd(&cnt[dst], 1);
    if (pos < CAP) {
        bucket[dst * CAP + pos] = src;
    } else {
        int sp = atomicAdd(&flags[2], 1);
        if (sp < SPILLCAP) { spill[2 * sp] = dst; spill[2 * sp + 1] = src; }
    }
}

// ---------------- fused GEMM + alpha: 32 rows/block, B-fragment reuse x2 ----------------
__global__ __launch_bounds__(256) void k_gemm_alpha(const void* __restrict__ X,
                                                    const unsigned short* __restrict__ WT,
                                                    const void* __restrict__ atts,
                                                    const void* __restrict__ attd,
                                                    int layer,
                                                    unsigned short* __restrict__ Hb,
                                                    float* __restrict__ as_, float* __restrict__ ad_,
                                                    int N, const int* __restrict__ flags) {
    __shared__ float lds_s[4][2][16], lds_d[4][2][16];
    __shared__ unsigned short cbuf[4][2][16][72];
    int fx = flags[0];
    int mt = blockIdx.x;
    int wave = threadIdx.x >> 6;
    int lane = threadIdx.x & 63;
    int r16 = lane & 15, quad = lane >> 4;
    int m0 = mt << 5;                       // 32 rows per block
    short8 a[2][4];
#pragma unroll
    for (int mi = 0; mi < 2; mi++) {
        int arow = m0 + mi * 16 + r16; if (arow >= N) arow = N - 1;
        if (fx) {
            const float* Xf = (const float*)X;
#pragma unroll
            for (int kk = 0; kk < 4; kk++) {
                const float4v* pv = (const float4v*)(Xf + (size_t)arow * 128 + kk * 32 + quad * 8);
                float4v lo = pv[0], hi = pv[1];
                short8 t;
                t[0] = (short)f2bf(lo[0]); t[1] = (short)f2bf(lo[1]);
                t[2] = (short)f2bf(lo[2]); t[3] = (short)f2bf(lo[3]);
                t[4] = (short)f2bf(hi[0]); t[5] = (short)f2bf(hi[1]);
                t[6] = (short)f2bf(hi[2]); t[7] = (short)f2bf(hi[3]);
                a[mi][kk] = t;
            }
        } else {
            const unsigned short* Xh = (const unsigned short*)X;
#pragma unroll
            for (int kk = 0; kk < 4; kk++)
                a[mi][kk] = *(const short8*)(Xh + (size_t)arow * 128 + kk * 32 + quad * 8);
        }
    }
    int head = wave >> 1;
    float ps[2][4] = {{0.f,0.f,0.f,0.f},{0.f,0.f,0.f,0.f}};
    float pd[2][4] = {{0.f,0.f,0.f,0.f},{0.f,0.f,0.f,0.f}};
#pragma unroll
    for (int nn = 0; nn < 4; nn++) {
        int nt = wave * 4 + nn;
        float4v acc0 = {0.f, 0.f, 0.f, 0.f};
        float4v acc1 = {0.f, 0.f, 0.f, 0.f};
#pragma unroll
        for (int kk = 0; kk < 4; kk++) {
            short8 b = *(const short8*)(WT + (nt * 16 + r16) * 128 + kk * 32 + quad * 8);
            acc0 = __builtin_amdgcn_mfma_f32_16x16x32_bf16(a[0][kk], b, acc0, 0, 0, 0);
            acc1 = __builtin_amdgcn_mfma_f32_16x16x32_bf16(a[1][kk], b, acc1, 0, 0, 0);
        }
        int c = (nt * 16 + r16) & 127;
        float sa, da;
        if (fx) {
            sa = ((const float*)atts)[layer * 256 + head * 128 + c];
            da = ((const float*)attd)[layer * 256 + head * 128 + c];
        } else {
            sa = bf2f(((const unsigned short*)atts)[layer * 256 + head * 128 + c]);
            da = bf2f(((const unsigned short*)attd)[layer * 256 + head * 128 + c]);
        }
#pragma unroll
        for (int r = 0; r < 4; r++) {
            // C/D: col=lane&15, row=quad*4+r [m89]
            cbuf[wave][0][quad * 4 + r][nn * 16 + r16] = f2bf(acc0[r]);
            cbuf[wave][1][quad * 4 + r][nn * 16 + r16] = f2bf(acc1[r]);
            ps[0][r] += acc0[r] * sa;  pd[0][r] += acc0[r] * da;
            ps[1][r] += acc1[r] * sa;  pd[1][r] += acc1[r] * da;
        }
    }
#pragma unroll
    for (int mi = 0; mi < 2; mi++) {
#pragma unroll
        for (int it = 0; it < 2; it++) {
            int idx = it * 64 + lane;
            int row = idx >> 3, chunk = idx & 7;
            uint4 v = *(const uint4*)&cbuf[wave][mi][row][chunk * 8];
            int grow = m0 + mi * 16 + row;
            if (grow < N)
                *(uint4*)(Hb + (size_t)grow * 256 + wave * 64 + chunk * 8) = v;
        }
    }
#pragma unroll
    for (int m = 1; m < 16; m <<= 1) {
#pragma unroll
        for (int mi = 0; mi < 2; mi++)
#pragma unroll
            for (int r = 0; r < 4; r++) {
                ps[mi][r] += __shfl_xor(ps[mi][r], m);
                pd[mi][r] += __shfl_xor(pd[mi][r], m);
            }
    }
    if (r16 == 0) {
#pragma unroll
        for (int mi = 0; mi < 2; mi++)
#pragma unroll
            for (int r = 0; r < 4; r++) {
                lds_s[wave][mi][quad * 4 + r] = ps[mi][r];
                lds_d[wave][mi][quad * 4 + r] = pd[mi][r];
            }
    }
    __syncthreads();
    if (threadIdx.x < 32) {
        int mi = threadIdx.x >> 4, rr = threadIdx.x & 15;
        int row = m0 + mi * 16 + rr;
        if (row < N) {
            float2 sv = { lds_s[0][mi][rr] + lds_s[1][mi][rr],
                          lds_s[2][mi][rr] + lds_s[3][mi][rr] };
            float2 dv = { lds_d[0][mi][rr] + lds_d[1][mi][rr],
                          lds_d[2][mi][rr] + lds_d[3][mi][rr] };
            *(float2*)(as_ + 2 * row) = sv;
            *(float2*)(ad_ + 2 * row) = dv;
        }
    }
}

// ---------------- hot aggregate: deg<=CAP only; R10 gather; trimmed preamble ----------------
static __device__ __forceinline__ void acc8(float* A, float w, uint4 q) {
    A[0] += w * bflo(q.x); A[1] += w * bfhi(q.x);
    A[2] += w * bflo(q.y); A[3] += w * bfhi(q.y);
    A[4] += w * bflo(q.z); A[5] += w * bfhi(q.z);
    A[6] += w * bflo(q.w); A[7] += w * bfhi(q.w);
}

__global__ __launch_bounds__(256) void k_aggregate(const unsigned short* __restrict__ Hb,
                                                   const float* __restrict__ as_, const float* __restrict__ ad_,
                                                   const int* __restrict__ cnt, const int* __restrict__ bucket,
                                                   const void* __restrict__ bias, int layer,
                                                   const int* __restrict__ flags,
                                                   void* __restrict__ outp, int N) {
    int fx = flags[0];
    int n = blockIdx.x * 4 + (threadIdx.x >> 6);
    if (n >= N) return;
    int deg = cnt[n];
    if (deg > CAP) return;           // handled by k_spillfix
    int lane = threadIdx.x & 63;
    int g = lane >> 4;
    int gl = lane & 15;              // owns channels [gl*8, gl*8+8) of each head
    const int* eb = bucket + n * CAP;
    float2 adv = *(const float2*)(ad_ + 2 * n);
    float ad0 = adv.x, ad1 = adv.y;

    // logits (single sweep: deg <= 48 <= 64 lanes)
    bool act = lane < deg;
    int s = 0; float l0 = -1e30f, l1 = -1e30f;
    if (act) {
        s = eb[lane]; if ((unsigned)s >= (unsigned)N) s = 0;
        float2 av = *(const float2*)(as_ + 2 * s);
        l0 = leaky(av.x + ad0); l1 = leaky(av.y + ad1);
    }
    // max-sub is mathematically redundant (alpha = exp(l)/sum exp(l)); skip the 12-bpermute
    // max reduction unless logits are large enough to overflow exp (never for sane inputs).
    float m0 = 0.f, m1 = 0.f;
    if (__any(fmaxf(l0, l1) > 30.f)) {
        m0 = l0; m1 = l1;
#pragma unroll
        for (int m = 1; m < 64; m <<= 1) { m0 = fmaxf(m0, __shfl_xor(m0, m)); m1 = fmaxf(m1, __shfl_xor(m1, m)); }
    }
    float w0 = act ? __expf(l0 - m0) : 0.f;   // weight==0 for lanes >= deg
    float w1 = act ? __expf(l1 - m1) : 0.f;
    // z sum-reduce DEFERRED to after the gather loop (only needed in epilogue)

    // R10 gather: single prefetch slot, divergent-while, exact trip count
    float acc0[8] = {0,0,0,0,0,0,0,0}, acc1[8] = {0,0,0,0,0,0,0,0};
    int e = g;
    bool v = e < deg;
    float wq0 = __shfl(w0, e), wq1 = __shfl(w1, e);
    int sq = __shfl(s, e);
    uint4 q0, q1;
    if (v) {
        const unsigned short* row = Hb + ((size_t)sq << 8);
        q0 = *(const uint4*)(row + gl * 8);
        q1 = *(const uint4*)(row + 128 + gl * 8);
    }
    while (v) {
        int en = e + 4;
        bool vn = en < deg;
        float wn0 = __shfl(w0, en & 63), wn1 = __shfl(w1, en & 63);
        int sn = __shfl(s, en & 63);
        uint4 p0, p1;
        if (vn) {
            const unsigned short* row = Hb + ((size_t)sn << 8);
            p0 = *(const uint4*)(row + gl * 8);
            p1 = *(const uint4*)(row + 128 + gl * 8);
        }
        acc8(acc0, wq0, q0);
        acc8(acc1, wq1, q1);
        e = en; v = vn; wq0 = wn0; wq1 = wn1; q0 = p0; q1 = p1;
    }

    // deferred softmax denominator
    float z0 = w0, z1 = w1;
#pragma unroll
    for (int m = 1; m < 64; m <<= 1) { z0 += __shfl_xor(z0, m); z1 += __shfl_xor(z1, m); }
    float inv0 = 1.f / (z0 + 1e-16f), inv1 = 1.f / (z1 + 1e-16f);
#pragma unroll
    for (int k = 0; k < 8; k++) {
        acc0[k] += __shfl_xor(acc0[k], 16); acc0[k] += __shfl_xor(acc0[k], 32);
        acc1[k] += __shfl_xor(acc1[k], 16); acc1[k] += __shfl_xor(acc1[k], 32);
    }

    float vv[8];
    if (fx) {
        const float* bf = (const float*)bias + layer * 128 + gl * 8;
#pragma unroll
        for (int k = 0; k < 8; k++) vv[k] = 0.5f * (acc0[k] * inv0 + acc1[k] * inv1) + bf[k];
    } else {
        const unsigned short* bh = (const unsigned short*)bias + layer * 128 + gl * 8;
        uint4 bv = *(const uint4*)bh;
        float bfv[8] = { bflo(bv.x), bfhi(bv.x), bflo(bv.y), bfhi(bv.y),
                         bflo(bv.z), bfhi(bv.z), bflo(bv.w), bfhi(bv.w) };
#pragma unroll
        for (int k = 0; k < 8; k++) vv[k] = 0.5f * (acc0[k] * inv0 + acc1[k] * inv1) + bfv[k];
    }

    float ss = 0.f;
#pragma unroll
    for (int k = 0; k < 8; k++) ss += vv[k] * vv[k];
#pragma unroll
    for (int m = 1; m < 16; m <<= 1) ss += __shfl_xor(ss, m);
    float inv = 1.f / fmaxf(sqrtf(ss), 1e-12f);

    if (lane < 16) {
        if (fx) {
            float* op = (float*)outp + (size_t)n * 128 + gl * 8;
            float4 o0 = { vv[0] * inv, vv[1] * inv, vv[2] * inv, vv[3] * inv };
            float4 o1 = { vv[4] * inv, vv[5] * inv, vv[6] * inv, vv[7] * inv };
            *(float4*)op = o0;
            *(float4*)(op + 4) = o1;
        } else {
            unsigned short* op = (unsigned short*)outp + (size_t)n * 128 + gl * 8;
            uint4 pk;
            pk.x = (unsigned int)f2bf(vv[0] * inv) | ((unsigned int)f2bf(vv[1] * inv) << 16);
            pk.y = (unsigned int)f2bf(vv[2] * inv) | ((unsigned int)f2bf(vv[3] * inv) << 16);
            pk.z = (unsigned int)f2bf(vv[4] * inv) | ((unsigned int)f2bf(vv[5] * inv) << 16);
            pk.w = (unsigned int)f2bf(vv[6] * inv) | ((unsigned int)f2bf(vv[7] * inv) << 16);
            *(uint4*)op = pk;
        }
    }
}

// ---------------- spill fix: only nodes with deg > CAP (statistically never) ----------------
__global__ __launch_bounds__(256) void k_spillfix(const unsigned short* __restrict__ Hb,
                                                  const float* __restrict__ as_, const float* __restrict__ ad_,
                                                  const int* __restrict__ cnt, const int* __restrict__ bucket,
                                                  const int* __restrict__ spill, const int* __restrict__ flags,
                                                  const void* __restrict__ bias, int layer,
                                                  void* __restrict__ outp, int N) {
    if (flags[2] == 0) return;       // no spills anywhere: hot kernel covered every node
    int fx = flags[0];
    int n = blockIdx.x * 4 + (threadIdx.x >> 6);
    if (n >= N) return;
    int deg = cnt[n];
    if (deg <= CAP) return;          // hot kernel handled it
    int lane = threadIdx.x & 63;
    int g = lane >> 4;
    int gl = lane & 15;
    const int* eb = bucket + n * CAP;
    int sc = flags[2]; if (sc > SPILLCAP) sc = SPILLCAP;
    float2 adv = *(const float2*)(ad_ + 2 * n);
    float ad0 = adv.x, ad1 = adv.y;

    float m0 = -1e30f, m1 = -1e30f;
    for (int i = lane; i < CAP; i += 64) {
        int s = eb[i]; if ((unsigned)s >= (unsigned)N) s = 0;
        float2 av = *(const float2*)(as_ + 2 * s);
        m0 = fmaxf(m0, leaky(av.x + ad0));
        m1 = fmaxf(m1, leaky(av.y + ad1));
    }
    for (int i = lane; i < sc; i += 64) {
        if (spill[2 * i] == n) {
            int s = spill[2 * i + 1]; if ((unsigned)s >= (unsigned)N) s = 0;
            float2 av = *(const float2*)(as_ + 2 * s);
            m0 = fmaxf(m0, leaky(av.x + ad0));
            m1 = fmaxf(m1, leaky(av.y + ad1));
        }
    }
#pragma unroll
    for (int m = 1; m < 64; m <<= 1) { m0 = fmaxf(m0, __shfl_xor(m0, m)); m1 = fmaxf(m1, __shfl_xor(m1, m)); }

    float acc0[8] = {0,0,0,0,0,0,0,0}, acc1[8] = {0,0,0,0,0,0,0,0};
    float z0 = 0.f, z1 = 0.f;
    {
        bool act = lane < CAP;
        int s = 0; float w0 = 0.f, w1 = 0.f;
        if (act) {
            s = eb[lane]; if ((unsigned)s >= (unsigned)N) s = 0;
            float2 av = *(const float2*)(as_ + 2 * s);
            w0 = __expf(leaky(av.x + ad0) - m0);
            w1 = __expf(leaky(av.y + ad1) - m1);
            z0 += w0; z1 += w1;
        }
        for (int j = 0; 4 * j < CAP; j++) {
            int e = 4 * j + g;
            int sq    = __shfl(s, e);
            float wq0 = __shfl(w0, e);
            float wq1 = __shfl(w1, e);
            if (e < CAP) {
                const unsigned short* row = Hb + ((size_t)sq << 8);
                uint4 q0 = *(const uint4*)(row + gl * 8);
                uint4 q1 = *(const uint4*)(row + 128 + gl * 8);
                acc8(acc0, wq0, q0);
                acc8(acc1, wq1, q1);
            }
        }
    }
    for (int i = 0; i < sc; i++) {
        int d = spill[2 * i];
        if (d != n) continue;
        int s = spill[2 * i + 1]; if ((unsigned)s >= (unsigned)N) s = 0;
        float2 av = *(const float2*)(as_ + 2 * s);
        float w0 = __expf(leaky(av.x + ad0) - m0);
        float w1 = __expf(leaky(av.y + ad1) - m1);
        if (lane == 0) { z0 += w0; z1 += w1; }
        if (g == 0) {
            const unsigned short* row = Hb + ((size_t)s << 8);
            uint4 q0 = *(const uint4*)(row + gl * 8);
            uint4 q1 = *(const uint4*)(row + 128 + gl * 8);
            acc8(acc0, w0, q0);
            acc8(acc1, w1, q1);
        }
    }
#pragma unroll
    for (int m = 1; m < 64; m <<= 1) { z0 += __shfl_xor(z0, m); z1 += __shfl_xor(z1, m); }

    float inv0 = 1.f / (z0 + 1e-16f), inv1 = 1.f / (z1 + 1e-16f);
#pragma unroll
    for (int k = 0; k < 8; k++) {
        acc0[k] += __shfl_xor(acc0[k], 16); acc0[k] += __shfl_xor(acc0[k], 32);
        acc1[k] += __shfl_xor(acc1[k], 16); acc1[k] += __shfl_xor(acc1[k], 32);
    }
    float vv[8];
    if (fx) {
        const float* bf = (const float*)bias + layer * 128 + gl * 8;
#pragma unroll
        for (int k = 0; k < 8; k++) vv[k] = 0.5f * (acc0[k] * inv0 + acc1[k] * inv1) + bf[k];
    } else {
        const unsigned short* bh = (const unsigned short*)bias + layer * 128 + gl * 8;
        uint4 bv = *(const uint4*)bh;
        float bfv[8] = { bflo(bv.x), bfhi(bv.x), bflo(bv.y), bfhi(bv.y),
                         bflo(bv.z), bfhi(bv.z), bflo(bv.w), bfhi(bv.w) };
#pragma unroll
        for (int k = 0; k < 8; k++) vv[k] = 0.5f * (acc0[k] * inv0 + acc1[k] * inv1) + bfv[k];
    }
    float ss = 0.f;
#pragma unroll
    for (int k = 0; k < 8; k++) ss += vv[k] * vv[k];
#pragma unroll
    for (int m = 1; m < 16; m <<= 1) ss += __shfl_xor(ss, m);
    float inv = 1.f / fmaxf(sqrtf(ss), 1e-12f);
    if (lane < 16) {
        if (fx) {
            float* op = (float*)outp + (size_t)n * 128 + gl * 8;
            float4 o0 = { vv[0] * inv, vv[1] * inv, vv[2] * inv, vv[3] * inv };
            float4 o1 = { vv[4] * inv, vv[5] * inv, vv[6] * inv, vv[7] * inv };
            *(float4*)op = o0;
            *(float4*)(op + 4) = o1;
        } else {
            unsigned short* op = (unsigned short*)outp + (size_t)n * 128 + gl * 8;
            uint4 pk;
            pk.x = (unsigned int)f2bf(vv[0] * inv) | ((unsigned int)f2bf(vv[1] * inv) << 16);
            pk.y = (unsigned int)f2bf(vv[2] * inv) | ((unsigned int)f2bf(vv[3] * inv) << 16);
            pk.z = (unsigned int)f2bf(vv[4] * inv) | ((unsigned int)f2bf(vv[5] * inv) << 16);
            pk.w = (unsigned int)f2bf(vv[6] * inv) | ((unsigned int)f2bf(vv[7] * inv) << 16);
            *(uint4*)op = pk;
        }
    }
}

extern "C" void kernel_launch(void* const* d_in, const int* in_sizes, int n_in,
                              void* d_out, int out_size, void* d_ws, size_t ws_size,
                              hipStream_t stream) {
    const void* x    = d_in[0];
    const int*  ei   = (const int*)d_in[1];
    const void* W    = d_in[2];
    const void* atts = d_in[3];
    const void* attd = d_in[4];
    const void* bias = d_in[5];

    int N = in_sizes[0] / 128;
    int E = in_sizes[1] / 2;

    char* p = (char*)d_ws;
    auto alloc = [&](size_t bytes) -> char* {
        char* q = p; p += (bytes + 255) & ~(size_t)255; return q;
    };
    int* flags   = (int*)alloc(256);                                   // [0]=fx [1]=is64 [2]=spillcnt
    int* cnt     = (int*)alloc((size_t)N * 4);
    float* as_   = (float*)alloc((size_t)N * 2 * 4);
    float* ad_   = (float*)alloc((size_t)N * 2 * 4);
    unsigned short* wt = (unsigned short*)alloc(2 * 256 * 128 * 2);
    int* spill   = (int*)alloc((size_t)SPILLCAP * 2 * 4);              // 512 KB
    int* bucket  = (int*)alloc((size_t)N * CAP * 4);                   // 9.6 MB
    unsigned short* hbuf = (unsigned short*)alloc((size_t)N * 256 * 2);// 25.6 MB
    // total ~36.9 MB

    k_probe_zero<<<(N + 255) / 256, 256, 0, stream>>>((const unsigned int*)x, ei, flags, cnt, N);
    k_bucket<<<(E + N + 255) / 256, 256, 0, stream>>>(ei, E, N, flags, cnt, bucket, spill, W, wt);

    int mtiles = (N + 31) / 32;
    int ngrp = (N + 3) / 4;
    for (int l = 0; l < 2; l++) {
        const void* xin = (l == 0) ? x : (const void*)d_out;
        k_gemm_alpha<<<mtiles, 256, 0, stream>>>(xin, wt + l * 32768, atts, attd, l,
                                                 hbuf, as_, ad_, N, flags);
        k_aggregate<<<ngrp, 256, 0, stream>>>(hbuf, as_, ad_, cnt, bucket,
                                              bias, l, flags, d_out, N);
        k_spillfix<<<ngrp, 256, 0, stream>>>(hbuf, as_, ad_, cnt, bucket, spill, flags,
                                             bias, l, d_out, N);
    }
}

// Round 6
// 328.994 us; speedup vs baseline: 1.1072x; 1.0092x over previous
//
#include <hip/hip_runtime.h>

// GAT, 2 layers, H=2 heads, D=C=128, concat=False (head mean), L2 normalize after each layer.
// Float tensors: fp32 OR bf16 (runtime-probed). edge_index: int32 OR int64 (runtime-probed).
// Internal h-matrix bf16 row-major [N][256].
// R16: k_bucket batched 4 edges/thread — 4 independent atomicAdds in flight per lane
// (was 1: pure latency chain, VALUBusy 0.7%). Everything else identical to R15.

#define CAP 48
#define SPILLCAP 65536

using short8  = __attribute__((ext_vector_type(8))) short;
using float4v = __attribute__((ext_vector_type(4))) float;

static __device__ __forceinline__ float bf2f(unsigned int u16) {
    union { unsigned int i; float f; } v; v.i = u16 << 16; return v.f;
}
static __device__ __forceinline__ float bflo(unsigned int p){
    union { unsigned int i; float f; } v; v.i = p << 16; return v.f;
}
static __device__ __forceinline__ float bfhi(unsigned int p){
    union { unsigned int i; float f; } v; v.i = p & 0xffff0000u; return v.f;
}
static __device__ __forceinline__ unsigned short f2bf(float f) {
    union { float f; unsigned int i; } v; v.f = f;
    unsigned int x = v.i;
    x += 0x7fffu + ((x >> 16) & 1u);   // RNE
    return (unsigned short)(x >> 16);
}
static __device__ __forceinline__ float leaky(float x){ return x > 0.f ? x : 0.2f * x; }

// ---------------- probe dtypes + zero cnt/spillcnt (fused) ----------------
__global__ __launch_bounds__(256) void k_probe_zero(const unsigned int* __restrict__ xw,
                                                    const int* __restrict__ ei,
                                                    int* __restrict__ flags,
                                                    int* __restrict__ cnt, int N) {
    int i = blockIdx.x * 256 + threadIdx.x;
    if (i < N) cnt[i] = 0;
    if (blockIdx.x == 0) {
        __shared__ int insane, oddnz;
        int t = threadIdx.x;
        if (t == 0) { insane = 0; oddnz = 0; }
        __syncthreads();
        unsigned int w = xw[t];
        if (((w >> 7) & 0xFFu) >= 154u) atomicOr(&insane, 1);
        if (ei[2 * t + 1] != 0) atomicOr(&oddnz, 1);
        __syncthreads();
        if (t == 0) { flags[0] = insane ? 1 : 0; flags[1] = oddnz ? 0 : 1; flags[2] = 0; }
    }
}

// ---------------- bucket scatter (4 edges/thread) + W->WT transpose (fused) ----------------
static __device__ __forceinline__ int edge_dst(const int* ei, int E, int i, int is64) {
    return is64 ? ei[2 * E + 2 * i] : ei[E + i];
}
static __device__ __forceinline__ int edge_src(const int* ei, int E, int i, int is64) {
    return is64 ? ei[2 * i] : ei[i];
}

__global__ __launch_bounds__(256) void k_bucket(const int* __restrict__ ei, int E, int N,
                                                int* __restrict__ flags,
                                                int* __restrict__ cnt,
                                                int* __restrict__ bucket,
                                                int* __restrict__ spill,
                                                const void* __restrict__ W,
                                                unsigned short* __restrict__ WT) {
    int base = (blockIdx.x * 256 + threadIdx.x) * 4;
    int fx = flags[0];
    int is64 = flags[1];
#pragma unroll
    for (int jj = 0; jj < 4; jj++) {
        int i = base + jj;
        if (i < 65536) {
            // transpose: WT[l][n][k] = W[l][k][n]  (2 layers x 128 x 256)
            int layer = i >> 15;
            int rem = i & 32767;
            int k = rem >> 8, n = rem & 255;
            int srci = layer * 32768 + k * 256 + n;
            unsigned short v;
            if (fx) v = f2bf(((const float*)W)[srci]);
            else    v = ((const unsigned short*)W)[srci];
            WT[layer * 32768 + n * 128 + k] = v;
        }
    }
    int srcs[4], dsts[4];
    bool act[4];
#pragma unroll
    for (int jj = 0; jj < 4; jj++) {
        int i = base + jj;
        act[jj] = (i < E + N);
        int s = 0, d = 0;
        if (act[jj]) {
            if (i < E) {
                s = edge_src(ei, E, i, is64);
                d = edge_dst(ei, E, i, is64);
                if ((unsigned)s >= (unsigned)N) s = 0;
                if ((unsigned)d >= (unsigned)N) d = 0;
            } else { s = d = i - E; }   // self loop
        }
        srcs[jj] = s; dsts[jj] = d;
    }
    int pos[4];
#pragma unroll
    for (int jj = 0; jj < 4; jj++)
        if (act[jj]) pos[jj] = atomicAdd(&cnt[dsts[jj]], 1);
#pragma unroll
    for (int jj = 0; jj < 4; jj++) {
        if (!act[jj]) continue;
        if (pos[jj] < CAP) {
            bucket[dsts[jj] * CAP + pos[jj]] = srcs[jj];
        } else {
            int sp = atomicAdd(&flags[2], 1);
            if (sp < SPILLCAP) { spill[2 * sp] = dsts[jj]; spill[2 * sp + 1] = srcs[jj]; }
        }
    }
}

// ---------------- fused GEMM + alpha: 32 rows/block, B-fragment reuse x2 ----------------
__global__ __launch_bounds__(256) void k_gemm_alpha(const void* __restrict__ X,
                                                    const unsigned short* __restrict__ WT,
                                                    const void* __restrict__ atts,
                                                    const void* __restrict__ attd,
                                                    int layer,
                                                    unsigned short* __restrict__ Hb,
                                                    float* __restrict__ as_, float* __restrict__ ad_,
                                                    int N, const int* __restrict__ flags) {
    __shared__ float lds_s[4][2][16], lds_d[4][2][16];
    __shared__ unsigned short cbuf[4][2][16][72];
    int fx = flags[0];
    int mt = blockIdx.x;
    int wave = threadIdx.x >> 6;
    int lane = threadIdx.x & 63;
    int r16 = lane & 15, quad = lane >> 4;
    int m0 = mt << 5;                       // 32 rows per block
    short8 a[2][4];
#pragma unroll
    for (int mi = 0; mi < 2; mi++) {
        int arow = m0 + mi * 16 + r16; if (arow >= N) arow = N - 1;
        if (fx) {
            const float* Xf = (const float*)X;
#pragma unroll
            for (int kk = 0; kk < 4; kk++) {
                const float4v* pv = (const float4v*)(Xf + (size_t)arow * 128 + kk * 32 + quad * 8);
                float4v lo = pv[0], hi = pv[1];
                short8 t;
                t[0] = (short)f2bf(lo[0]); t[1] = (short)f2bf(lo[1]);
                t[2] = (short)f2bf(lo[2]); t[3] = (short)f2bf(lo[3]);
                t[4] = (short)f2bf(hi[0]); t[5] = (short)f2bf(hi[1]);
                t[6] = (short)f2bf(hi[2]); t[7] = (short)f2bf(hi[3]);
                a[mi][kk] = t;
            }
        } else {
            const unsigned short* Xh = (const unsigned short*)X;
#pragma unroll
            for (int kk = 0; kk < 4; kk++)
                a[mi][kk] = *(const short8*)(Xh + (size_t)arow * 128 + kk * 32 + quad * 8);
        }
    }
    int head = wave >> 1;
    float ps[2][4] = {{0.f,0.f,0.f,0.f},{0.f,0.f,0.f,0.f}};
    float pd[2][4] = {{0.f,0.f,0.f,0.f},{0.f,0.f,0.f,0.f}};
#pragma unroll
    for (int nn = 0; nn < 4; nn++) {
        int nt = wave * 4 + nn;
        float4v acc0 = {0.f, 0.f, 0.f, 0.f};
        float4v acc1 = {0.f, 0.f, 0.f, 0.f};
#pragma unroll
        for (int kk = 0; kk < 4; kk++) {
            short8 b = *(const short8*)(WT + (nt * 16 + r16) * 128 + kk * 32 + quad * 8);
            acc0 = __builtin_amdgcn_mfma_f32_16x16x32_bf16(a[0][kk], b, acc0, 0, 0, 0);
            acc1 = __builtin_amdgcn_mfma_f32_16x16x32_bf16(a[1][kk], b, acc1, 0, 0, 0);
        }
        int c = (nt * 16 + r16) & 127;
        float sa, da;
        if (fx) {
            sa = ((const float*)atts)[layer * 256 + head * 128 + c];
            da = ((const float*)attd)[layer * 256 + head * 128 + c];
        } else {
            sa = bf2f(((const unsigned short*)atts)[layer * 256 + head * 128 + c]);
            da = bf2f(((const unsigned short*)attd)[layer * 256 + head * 128 + c]);
        }
#pragma unroll
        for (int r = 0; r < 4; r++) {
            // C/D: col=lane&15, row=quad*4+r [m89]
            cbuf[wave][0][quad * 4 + r][nn * 16 + r16] = f2bf(acc0[r]);
            cbuf[wave][1][quad * 4 + r][nn * 16 + r16] = f2bf(acc1[r]);
            ps[0][r] += acc0[r] * sa;  pd[0][r] += acc0[r] * da;
            ps[1][r] += acc1[r] * sa;  pd[1][r] += acc1[r] * da;
        }
    }
#pragma unroll
    for (int mi = 0; mi < 2; mi++) {
#pragma unroll
        for (int it = 0; it < 2; it++) {
            int idx = it * 64 + lane;
            int row = idx >> 3, chunk = idx & 7;
            uint4 v = *(const uint4*)&cbuf[wave][mi][row][chunk * 8];
            int grow = m0 + mi * 16 + row;
            if (grow < N)
                *(uint4*)(Hb + (size_t)grow * 256 + wave * 64 + chunk * 8) = v;
        }
    }
#pragma unroll
    for (int m = 1; m < 16; m <<= 1) {
#pragma unroll
        for (int mi = 0; mi < 2; mi++)
#pragma unroll
            for (int r = 0; r < 4; r++) {
                ps[mi][r] += __shfl_xor(ps[mi][r], m);
                pd[mi][r] += __shfl_xor(pd[mi][r], m);
            }
    }
    if (r16 == 0) {
#pragma unroll
        for (int mi = 0; mi < 2; mi++)
#pragma unroll
            for (int r = 0; r < 4; r++) {
                lds_s[wave][mi][quad * 4 + r] = ps[mi][r];
                lds_d[wave][mi][quad * 4 + r] = pd[mi][r];
            }
    }
    __syncthreads();
    if (threadIdx.x < 32) {
        int mi = threadIdx.x >> 4, rr = threadIdx.x & 15;
        int row = m0 + mi * 16 + rr;
        if (row < N) {
            float2 sv = { lds_s[0][mi][rr] + lds_s[1][mi][rr],
                          lds_s[2][mi][rr] + lds_s[3][mi][rr] };
            float2 dv = { lds_d[0][mi][rr] + lds_d[1][mi][rr],
                          lds_d[2][mi][rr] + lds_d[3][mi][rr] };
            *(float2*)(as_ + 2 * row) = sv;
            *(float2*)(ad_ + 2 * row) = dv;
        }
    }
}

// ---------------- hot aggregate: deg<=CAP only; R10 gather; trimmed preamble ----------------
static __device__ __forceinline__ void acc8(float* A, float w, uint4 q) {
    A[0] += w * bflo(q.x); A[1] += w * bfhi(q.x);
    A[2] += w * bflo(q.y); A[3] += w * bfhi(q.y);
    A[4] += w * bflo(q.z); A[5] += w * bfhi(q.z);
    A[6] += w * bflo(q.w); A[7] += w * bfhi(q.w);
}

__global__ __launch_bounds__(256) void k_aggregate(const unsigned short* __restrict__ Hb,
                                                   const float* __restrict__ as_, const float* __restrict__ ad_,
                                                   const int* __restrict__ cnt, const int* __restrict__ bucket,
                                                   const void* __restrict__ bias, int layer,
                                                   const int* __restrict__ flags,
                                                   void* __restrict__ outp, int N) {
    int fx = flags[0];
    int n = blockIdx.x * 4 + (threadIdx.x >> 6);
    if (n >= N) return;
    int deg = cnt[n];
    if (deg > CAP) return;           // handled by k_spillfix
    int lane = threadIdx.x & 63;
    int g = lane >> 4;
    int gl = lane & 15;              // owns channels [gl*8, gl*8+8) of each head
    const int* eb = bucket + n * CAP;
    float2 adv = *(const float2*)(ad_ + 2 * n);
    float ad0 = adv.x, ad1 = adv.y;

    // logits (single sweep: deg <= 48 <= 64 lanes)
    bool act = lane < deg;
    int s = 0; float l0 = -1e30f, l1 = -1e30f;
    if (act) {
        s = eb[lane]; if ((unsigned)s >= (unsigned)N) s = 0;
        float2 av = *(const float2*)(as_ + 2 * s);
        l0 = leaky(av.x + ad0); l1 = leaky(av.y + ad1);
    }
    // max-sub is mathematically redundant (alpha = exp(l)/sum exp(l)); skip the 12-bpermute
    // max reduction unless logits are large enough to overflow exp (never for sane inputs).
    float m0 = 0.f, m1 = 0.f;
    if (__any(fmaxf(l0, l1) > 30.f)) {
        m0 = l0; m1 = l1;
#pragma unroll
        for (int m = 1; m < 64; m <<= 1) { m0 = fmaxf(m0, __shfl_xor(m0, m)); m1 = fmaxf(m1, __shfl_xor(m1, m)); }
    }
    float w0 = act ? __expf(l0 - m0) : 0.f;   // weight==0 for lanes >= deg
    float w1 = act ? __expf(l1 - m1) : 0.f;
    // z sum-reduce DEFERRED to after the gather loop (only needed in epilogue)

    // R10 gather: single prefetch slot, divergent-while, exact trip count
    float acc0[8] = {0,0,0,0,0,0,0,0}, acc1[8] = {0,0,0,0,0,0,0,0};
    int e = g;
    bool v = e < deg;
    float wq0 = __shfl(w0, e), wq1 = __shfl(w1, e);
    int sq = __shfl(s, e);
    uint4 q0, q1;
    if (v) {
        const unsigned short* row = Hb + ((size_t)sq << 8);
        q0 = *(const uint4*)(row + gl * 8);
        q1 = *(const uint4*)(row + 128 + gl * 8);
    }
    while (v) {
        int en = e + 4;
        bool vn = en < deg;
        float wn0 = __shfl(w0, en & 63), wn1 = __shfl(w1, en & 63);
        int sn = __shfl(s, en & 63);
        uint4 p0, p1;
        if (vn) {
            const unsigned short* row = Hb + ((size_t)sn << 8);
            p0 = *(const uint4*)(row + gl * 8);
            p1 = *(const uint4*)(row + 128 + gl * 8);
        }
        acc8(acc0, wq0, q0);
        acc8(acc1, wq1, q1);
        e = en; v = vn; wq0 = wn0; wq1 = wn1; q0 = p0; q1 = p1;
    }

    // deferred softmax denominator
    float z0 = w0, z1 = w1;
#pragma unroll
    for (int m = 1; m < 64; m <<= 1) { z0 += __shfl_xor(z0, m); z1 += __shfl_xor(z1, m); }
    float inv0 = 1.f / (z0 + 1e-16f), inv1 = 1.f / (z1 + 1e-16f);
#pragma unroll
    for (int k = 0; k < 8; k++) {
        acc0[k] += __shfl_xor(acc0[k], 16); acc0[k] += __shfl_xor(acc0[k], 32);
        acc1[k] += __shfl_xor(acc1[k], 16); acc1[k] += __shfl_xor(acc1[k], 32);
    }

    float vv[8];
    if (fx) {
        const float* bf = (const float*)bias + layer * 128 + gl * 8;
#pragma unroll
        for (int k = 0; k < 8; k++) vv[k] = 0.5f * (acc0[k] * inv0 + acc1[k] * inv1) + bf[k];
    } else {
        const unsigned short* bh = (const unsigned short*)bias + layer * 128 + gl * 8;
        uint4 bv = *(const uint4*)bh;
        float bfv[8] = { bflo(bv.x), bfhi(bv.x), bflo(bv.y), bfhi(bv.y),
                         bflo(bv.z), bfhi(bv.z), bflo(bv.w), bfhi(bv.w) };
#pragma unroll
        for (int k = 0; k < 8; k++) vv[k] = 0.5f * (acc0[k] * inv0 + acc1[k] * inv1) + bfv[k];
    }

    float ss = 0.f;
#pragma unroll
    for (int k = 0; k < 8; k++) ss += vv[k] * vv[k];
#pragma unroll
    for (int m = 1; m < 16; m <<= 1) ss += __shfl_xor(ss, m);
    float inv = 1.f / fmaxf(sqrtf(ss), 1e-12f);

    if (lane < 16) {
        if (fx) {
            float* op = (float*)outp + (size_t)n * 128 + gl * 8;
            float4 o0 = { vv[0] * inv, vv[1] * inv, vv[2] * inv, vv[3] * inv };
            float4 o1 = { vv[4] * inv, vv[5] * inv, vv[6] * inv, vv[7] * inv };
            *(float4*)op = o0;
            *(float4*)(op + 4) = o1;
        } else {
            unsigned short* op = (unsigned short*)outp + (size_t)n * 128 + gl * 8;
            uint4 pk;
            pk.x = (unsigned int)f2bf(vv[0] * inv) | ((unsigned int)f2bf(vv[1] * inv) << 16);
            pk.y = (unsigned int)f2bf(vv[2] * inv) | ((unsigned int)f2bf(vv[3] * inv) << 16);
            pk.z = (unsigned int)f2bf(vv[4] * inv) | ((unsigned int)f2bf(vv[5] * inv) << 16);
            pk.w = (unsigned int)f2bf(vv[6] * inv) | ((unsigned int)f2bf(vv[7] * inv) << 16);
            *(uint4*)op = pk;
        }
    }
}

// ---------------- spill fix: only nodes with deg > CAP (statistically never) ----------------
__global__ __launch_bounds__(256) void k_spillfix(const unsigned short* __restrict__ Hb,
                                                  const float* __restrict__ as_, const float* __restrict__ ad_,
                                                  const int* __restrict__ cnt, const int* __restrict__ bucket,
                                                  const int* __restrict__ spill, const int* __restrict__ flags,
                                                  const void* __restrict__ bias, int layer,
                                                  void* __restrict__ outp, int N) {
    if (flags[2] == 0) return;       // no spills anywhere: hot kernel covered every node
    int fx = flags[0];
    int n = blockIdx.x * 4 + (threadIdx.x >> 6);
    if (n >= N) return;
    int deg = cnt[n];
    if (deg <= CAP) return;          // hot kernel handled it
    int lane = threadIdx.x & 63;
    int g = lane >> 4;
    int gl = lane & 15;
    const int* eb = bucket + n * CAP;
    int sc = flags[2]; if (sc > SPILLCAP) sc = SPILLCAP;
    float2 adv = *(const float2*)(ad_ + 2 * n);
    float ad0 = adv.x, ad1 = adv.y;

    float m0 = -1e30f, m1 = -1e30f;
    for (int i = lane; i < CAP; i += 64) {
        int s = eb[i]; if ((unsigned)s >= (unsigned)N) s = 0;
        float2 av = *(const float2*)(as_ + 2 * s);
        m0 = fmaxf(m0, leaky(av.x + ad0));
        m1 = fmaxf(m1, leaky(av.y + ad1));
    }
    for (int i = lane; i < sc; i += 64) {
        if (spill[2 * i] == n) {
            int s = spill[2 * i + 1]; if ((unsigned)s >= (unsigned)N) s = 0;
            float2 av = *(const float2*)(as_ + 2 * s);
            m0 = fmaxf(m0, leaky(av.x + ad0));
            m1 = fmaxf(m1, leaky(av.y + ad1));
        }
    }
#pragma unroll
    for (int m = 1; m < 64; m <<= 1) { m0 = fmaxf(m0, __shfl_xor(m0, m)); m1 = fmaxf(m1, __shfl_xor(m1, m)); }

    float acc0[8] = {0,0,0,0,0,0,0,0}, acc1[8] = {0,0,0,0,0,0,0,0};
    float z0 = 0.f, z1 = 0.f;
    {
        bool act = lane < CAP;
        int s = 0; float w0 = 0.f, w1 = 0.f;
        if (act) {
            s = eb[lane]; if ((unsigned)s >= (unsigned)N) s = 0;
            float2 av = *(const float2*)(as_ + 2 * s);
            w0 = __expf(leaky(av.x + ad0) - m0);
            w1 = __expf(leaky(av.y + ad1) - m1);
            z0 += w0; z1 += w1;
        }
        for (int j = 0; 4 * j < CAP; j++) {
            int e = 4 * j + g;
            int sq    = __shfl(s, e);
            float wq0 = __shfl(w0, e);
            float wq1 = __shfl(w1, e);
            if (e < CAP) {
                const unsigned short* row = Hb + ((size_t)sq << 8);
                uint4 q0 = *(const uint4*)(row + gl * 8);
                uint4 q1 = *(const uint4*)(row + 128 + gl * 8);
                acc8(acc0, wq0, q0);
                acc8(acc1, wq1, q1);
            }
        }
    }
    for (int i = 0; i < sc; i++) {
        int d = spill[2 * i];
        if (d != n) continue;
        int s = spill[2 * i + 1]; if ((unsigned)s >= (unsigned)N) s = 0;
        float2 av = *(const float2*)(as_ + 2 * s);
        float w0 = __expf(leaky(av.x + ad0) - m0);
        float w1 = __expf(leaky(av.y + ad1) - m1);
        if (lane == 0) { z0 += w0; z1 += w1; }
        if (g == 0) {
            const unsigned short* row = Hb + ((size_t)s << 8);
            uint4 q0 = *(const uint4*)(row + gl * 8);
            uint4 q1 = *(const uint4*)(row + 128 + gl * 8);
            acc8(acc0, w0, q0);
            acc8(acc1, w1, q1);
        }
    }
#pragma unroll
    for (int m = 1; m < 64; m <<= 1) { z0 += __shfl_xor(z0, m); z1 += __shfl_xor(z1, m); }

    float inv0 = 1.f / (z0 + 1e-16f), inv1 = 1.f / (z1 + 1e-16f);
#pragma unroll
    for (int k = 0; k < 8; k++) {
        acc0[k] += __shfl_xor(acc0[k], 16); acc0[k] += __shfl_xor(acc0[k], 32);
        acc1[k] += __shfl_xor(acc1[k], 16); acc1[k] += __shfl_xor(acc1[k], 32);
    }
    float vv[8];
    if (fx) {
        const float* bf = (const float*)bias + layer * 128 + gl * 8;
#pragma unroll
        for (int k = 0; k < 8; k++) vv[k] = 0.5f * (acc0[k] * inv0 + acc1[k] * inv1) + bf[k];
    } else {
        const unsigned short* bh = (const unsigned short*)bias + layer * 128 + gl * 8;
        uint4 bv = *(const uint4*)bh;
        float bfv[8] = { bflo(bv.x), bfhi(bv.x), bflo(bv.y), bfhi(bv.y),
                         bflo(bv.z), bfhi(bv.z), bflo(bv.w), bfhi(bv.w) };
#pragma unroll
        for (int k = 0; k < 8; k++) vv[k] = 0.5f * (acc0[k] * inv0 + acc1[k] * inv1) + bfv[k];
    }
    float ss = 0.f;
#pragma unroll
    for (int k = 0; k < 8; k++) ss += vv[k] * vv[k];
#pragma unroll
    for (int m = 1; m < 16; m <<= 1) ss += __shfl_xor(ss, m);
    float inv = 1.f / fmaxf(sqrtf(ss), 1e-12f);
    if (lane < 16) {
        if (fx) {
            float* op = (float*)outp + (size_t)n * 128 + gl * 8;
            float4 o0 = { vv[0] * inv, vv[1] * inv, vv[2] * inv, vv[3] * inv };
            float4 o1 = { vv[4] * inv, vv[5] * inv, vv[6] * inv, vv[7] * inv };
            *(float4*)op = o0;
            *(float4*)(op + 4) = o1;
        } else {
            unsigned short* op = (unsigned short*)outp + (size_t)n * 128 + gl * 8;
            uint4 pk;
            pk.x = (unsigned int)f2bf(vv[0] * inv) | ((unsigned int)f2bf(vv[1] * inv) << 16);
            pk.y = (unsigned int)f2bf(vv[2] * inv) | ((unsigned int)f2bf(vv[3] * inv) << 16);
            pk.z = (unsigned int)f2bf(vv[4] * inv) | ((unsigned int)f2bf(vv[5] * inv) << 16);
            pk.w = (unsigned int)f2bf(vv[6] * inv) | ((unsigned int)f2bf(vv[7] * inv) << 16);
            *(uint4*)op = pk;
        }
    }
}

extern "C" void kernel_launch(void* const* d_in, const int* in_sizes, int n_in,
                              void* d_out, int out_size, void* d_ws, size_t ws_size,
                              hipStream_t stream) {
    const void* x    = d_in[0];
    const int*  ei   = (const int*)d_in[1];
    const void* W    = d_in[2];
    const void* atts = d_in[3];
    const void* attd = d_in[4];
    const void* bias = d_in[5];

    int N = in_sizes[0] / 128;
    int E = in_sizes[1] / 2;

    char* p = (char*)d_ws;
    auto alloc = [&](size_t bytes) -> char* {
        char* q = p; p += (bytes + 255) & ~(size_t)255; return q;
    };
    int* flags   = (int*)alloc(256);                                   // [0]=fx [1]=is64 [2]=spillcnt
    int* cnt     = (int*)alloc((size_t)N * 4);
    float* as_   = (float*)alloc((size_t)N * 2 * 4);
    float* ad_   = (float*)alloc((size_t)N * 2 * 4);
    unsigned short* wt = (unsigned short*)alloc(2 * 256 * 128 * 2);
    int* spill   = (int*)alloc((size_t)SPILLCAP * 2 * 4);              // 512 KB
    int* bucket  = (int*)alloc((size_t)N * CAP * 4);                   // 9.6 MB
    unsigned short* hbuf = (unsigned short*)alloc((size_t)N * 256 * 2);// 25.6 MB
    // total ~36.9 MB

    k_probe_zero<<<(N + 255) / 256, 256, 0, stream>>>((const unsigned int*)x, ei, flags, cnt, N);
    int work = E + N; if (work < 65536) work = 65536;
    k_bucket<<<(work + 1023) / 1024, 256, 0, stream>>>(ei, E, N, flags, cnt, bucket, spill, W, wt);

    int mtiles = (N + 31) / 32;
    int ngrp = (N + 3) / 4;
    for (int l = 0; l < 2; l++) {
        const void* xin = (l == 0) ? x : (const void*)d_out;
        k_gemm_alpha<<<mtiles, 256, 0, stream>>>(xin, wt + l * 32768, atts, attd, l,
                                                 hbuf, as_, ad_, N, flags);
        k_aggregate<<<ngrp, 256, 0, stream>>>(hbuf, as_, ad_, cnt, bucket,
                                              bias, l, flags, d_out, N);
        k_spillfix<<<ngrp, 256, 0, stream>>>(hbuf, as_, ad_, cnt, bucket, spill, flags,
                                             bias, l, d_out, N);
    }
}

// Round 7
// 320.243 us; speedup vs baseline: 1.1375x; 1.0273x over previous
//
#include <hip/hip_runtime.h>

// GAT, 2 layers, H=2 heads, D=C=128, concat=False (head mean), L2 normalize after each layer.
// Float tensors: fp32 OR bf16 (runtime-probed). edge_index: int32 OR int64 (runtime-probed).
// Internal h-matrix bf16 row-major [N][256].
// R17: cnt padded to one counter per 64B cache line (cnt[dst*16]) — discriminating test of
// "device-scope atomics serialize per-line at the coherence point" (R15 vs R16 showed k_bucket
// is throughput-pinned at ~64us independent of parallelism). Same atomic count, same scatter.
// Everything else identical to R16.

#define CAP 48
#define SPILLCAP 65536

using short8  = __attribute__((ext_vector_type(8))) short;
using float4v = __attribute__((ext_vector_type(4))) float;

static __device__ __forceinline__ float bf2f(unsigned int u16) {
    union { unsigned int i; float f; } v; v.i = u16 << 16; return v.f;
}
static __device__ __forceinline__ float bflo(unsigned int p){
    union { unsigned int i; float f; } v; v.i = p << 16; return v.f;
}
static __device__ __forceinline__ float bfhi(unsigned int p){
    union { unsigned int i; float f; } v; v.i = p & 0xffff0000u; return v.f;
}
static __device__ __forceinline__ unsigned short f2bf(float f) {
    union { float f; unsigned int i; } v; v.f = f;
    unsigned int x = v.i;
    x += 0x7fffu + ((x >> 16) & 1u);   // RNE
    return (unsigned short)(x >> 16);
}
static __device__ __forceinline__ float leaky(float x){ return x > 0.f ? x : 0.2f * x; }

// ---------------- probe dtypes + zero cnt/spillcnt (fused) ----------------
__global__ __launch_bounds__(256) void k_probe_zero(const unsigned int* __restrict__ xw,
                                                    const int* __restrict__ ei,
                                                    int* __restrict__ flags,
                                                    int* __restrict__ cnt, int N) {
    int i = blockIdx.x * 256 + threadIdx.x;
    if (i < N) cnt[i * 16] = 0;          // one counter per 64B line
    if (blockIdx.x == 0) {
        __shared__ int insane, oddnz;
        int t = threadIdx.x;
        if (t == 0) { insane = 0; oddnz = 0; }
        __syncthreads();
        unsigned int w = xw[t];
        if (((w >> 7) & 0xFFu) >= 154u) atomicOr(&insane, 1);
        if (ei[2 * t + 1] != 0) atomicOr(&oddnz, 1);
        __syncthreads();
        if (t == 0) { flags[0] = insane ? 1 : 0; flags[1] = oddnz ? 0 : 1; flags[2] = 0; }
    }
}

// ---------------- bucket scatter (4 edges/thread) + W->WT transpose (fused) ----------------
static __device__ __forceinline__ int edge_dst(const int* ei, int E, int i, int is64) {
    return is64 ? ei[2 * E + 2 * i] : ei[E + i];
}
static __device__ __forceinline__ int edge_src(const int* ei, int E, int i, int is64) {
    return is64 ? ei[2 * i] : ei[i];
}

__global__ __launch_bounds__(256) void k_bucket(const int* __restrict__ ei, int E, int N,
                                                int* __restrict__ flags,
                                                int* __restrict__ cnt,
                                                int* __restrict__ bucket,
                                                int* __restrict__ spill,
                                                const void* __restrict__ W,
                                                unsigned short* __restrict__ WT) {
    int base = (blockIdx.x * 256 + threadIdx.x) * 4;
    int fx = flags[0];
    int is64 = flags[1];
#pragma unroll
    for (int jj = 0; jj < 4; jj++) {
        int i = base + jj;
        if (i < 65536) {
            // transpose: WT[l][n][k] = W[l][k][n]  (2 layers x 128 x 256)
            int layer = i >> 15;
            int rem = i & 32767;
            int k = rem >> 8, n = rem & 255;
            int srci = layer * 32768 + k * 256 + n;
            unsigned short v;
            if (fx) v = f2bf(((const float*)W)[srci]);
            else    v = ((const unsigned short*)W)[srci];
            WT[layer * 32768 + n * 128 + k] = v;
        }
    }
    int srcs[4], dsts[4];
    bool act[4];
#pragma unroll
    for (int jj = 0; jj < 4; jj++) {
        int i = base + jj;
        act[jj] = (i < E + N);
        int s = 0, d = 0;
        if (act[jj]) {
            if (i < E) {
                s = edge_src(ei, E, i, is64);
                d = edge_dst(ei, E, i, is64);
                if ((unsigned)s >= (unsigned)N) s = 0;
                if ((unsigned)d >= (unsigned)N) d = 0;
            } else { s = d = i - E; }   // self loop
        }
        srcs[jj] = s; dsts[jj] = d;
    }
    int pos[4];
#pragma unroll
    for (int jj = 0; jj < 4; jj++)
        if (act[jj]) pos[jj] = atomicAdd(&cnt[dsts[jj] * 16], 1);
#pragma unroll
    for (int jj = 0; jj < 4; jj++) {
        if (!act[jj]) continue;
        if (pos[jj] < CAP) {
            bucket[dsts[jj] * CAP + pos[jj]] = srcs[jj];
        } else {
            int sp = atomicAdd(&flags[2], 1);
            if (sp < SPILLCAP) { spill[2 * sp] = dsts[jj]; spill[2 * sp + 1] = srcs[jj]; }
        }
    }
}

// ---------------- fused GEMM + alpha: 32 rows/block, B-fragment reuse x2 ----------------
__global__ __launch_bounds__(256) void k_gemm_alpha(const void* __restrict__ X,
                                                    const unsigned short* __restrict__ WT,
                                                    const void* __restrict__ atts,
                                                    const void* __restrict__ attd,
                                                    int layer,
                                                    unsigned short* __restrict__ Hb,
                                                    float* __restrict__ as_, float* __restrict__ ad_,
                                                    int N, const int* __restrict__ flags) {
    __shared__ float lds_s[4][2][16], lds_d[4][2][16];
    __shared__ unsigned short cbuf[4][2][16][72];
    int fx = flags[0];
    int mt = blockIdx.x;
    int wave = threadIdx.x >> 6;
    int lane = threadIdx.x & 63;
    int r16 = lane & 15, quad = lane >> 4;
    int m0 = mt << 5;                       // 32 rows per block
    short8 a[2][4];
#pragma unroll
    for (int mi = 0; mi < 2; mi++) {
        int arow = m0 + mi * 16 + r16; if (arow >= N) arow = N - 1;
        if (fx) {
            const float* Xf = (const float*)X;
#pragma unroll
            for (int kk = 0; kk < 4; kk++) {
                const float4v* pv = (const float4v*)(Xf + (size_t)arow * 128 + kk * 32 + quad * 8);
                float4v lo = pv[0], hi = pv[1];
                short8 t;
                t[0] = (short)f2bf(lo[0]); t[1] = (short)f2bf(lo[1]);
                t[2] = (short)f2bf(lo[2]); t[3] = (short)f2bf(lo[3]);
                t[4] = (short)f2bf(hi[0]); t[5] = (short)f2bf(hi[1]);
                t[6] = (short)f2bf(hi[2]); t[7] = (short)f2bf(hi[3]);
                a[mi][kk] = t;
            }
        } else {
            const unsigned short* Xh = (const unsigned short*)X;
#pragma unroll
            for (int kk = 0; kk < 4; kk++)
                a[mi][kk] = *(const short8*)(Xh + (size_t)arow * 128 + kk * 32 + quad * 8);
        }
    }
    int head = wave >> 1;
    float ps[2][4] = {{0.f,0.f,0.f,0.f},{0.f,0.f,0.f,0.f}};
    float pd[2][4] = {{0.f,0.f,0.f,0.f},{0.f,0.f,0.f,0.f}};
#pragma unroll
    for (int nn = 0; nn < 4; nn++) {
        int nt = wave * 4 + nn;
        float4v acc0 = {0.f, 0.f, 0.f, 0.f};
        float4v acc1 = {0.f, 0.f, 0.f, 0.f};
#pragma unroll
        for (int kk = 0; kk < 4; kk++) {
            short8 b = *(const short8*)(WT + (nt * 16 + r16) * 128 + kk * 32 + quad * 8);
            acc0 = __builtin_amdgcn_mfma_f32_16x16x32_bf16(a[0][kk], b, acc0, 0, 0, 0);
            acc1 = __builtin_amdgcn_mfma_f32_16x16x32_bf16(a[1][kk], b, acc1, 0, 0, 0);
        }
        int c = (nt * 16 + r16) & 127;
        float sa, da;
        if (fx) {
            sa = ((const float*)atts)[layer * 256 + head * 128 + c];
            da = ((const float*)attd)[layer * 256 + head * 128 + c];
        } else {
            sa = bf2f(((const unsigned short*)atts)[layer * 256 + head * 128 + c]);
            da = bf2f(((const unsigned short*)attd)[layer * 256 + head * 128 + c]);
        }
#pragma unroll
        for (int r = 0; r < 4; r++) {
            // C/D: col=lane&15, row=quad*4+r [m89]
            cbuf[wave][0][quad * 4 + r][nn * 16 + r16] = f2bf(acc0[r]);
            cbuf[wave][1][quad * 4 + r][nn * 16 + r16] = f2bf(acc1[r]);
            ps[0][r] += acc0[r] * sa;  pd[0][r] += acc0[r] * da;
            ps[1][r] += acc1[r] * sa;  pd[1][r] += acc1[r] * da;
        }
    }
#pragma unroll
    for (int mi = 0; mi < 2; mi++) {
#pragma unroll
        for (int it = 0; it < 2; it++) {
            int idx = it * 64 + lane;
            int row = idx >> 3, chunk = idx & 7;
            uint4 v = *(const uint4*)&cbuf[wave][mi][row][chunk * 8];
            int grow = m0 + mi * 16 + row;
            if (grow < N)
                *(uint4*)(Hb + (size_t)grow * 256 + wave * 64 + chunk * 8) = v;
        }
    }
#pragma unroll
    for (int m = 1; m < 16; m <<= 1) {
#pragma unroll
        for (int mi = 0; mi < 2; mi++)
#pragma unroll
            for (int r = 0; r < 4; r++) {
                ps[mi][r] += __shfl_xor(ps[mi][r], m);
                pd[mi][r] += __shfl_xor(pd[mi][r], m);
            }
    }
    if (r16 == 0) {
#pragma unroll
        for (int mi = 0; mi < 2; mi++)
#pragma unroll
            for (int r = 0; r < 4; r++) {
                lds_s[wave][mi][quad * 4 + r] = ps[mi][r];
                lds_d[wave][mi][quad * 4 + r] = pd[mi][r];
            }
    }
    __syncthreads();
    if (threadIdx.x < 32) {
        int mi = threadIdx.x >> 4, rr = threadIdx.x & 15;
        int row = m0 + mi * 16 + rr;
        if (row < N) {
            float2 sv = { lds_s[0][mi][rr] + lds_s[1][mi][rr],
                          lds_s[2][mi][rr] + lds_s[3][mi][rr] };
            float2 dv = { lds_d[0][mi][rr] + lds_d[1][mi][rr],
                          lds_d[2][mi][rr] + lds_d[3][mi][rr] };
            *(float2*)(as_ + 2 * row) = sv;
            *(float2*)(ad_ + 2 * row) = dv;
        }
    }
}

// ---------------- hot aggregate: deg<=CAP only; R10 gather; trimmed preamble ----------------
static __device__ __forceinline__ void acc8(float* A, float w, uint4 q) {
    A[0] += w * bflo(q.x); A[1] += w * bfhi(q.x);
    A[2] += w * bflo(q.y); A[3] += w * bfhi(q.y);
    A[4] += w * bflo(q.z); A[5] += w * bfhi(q.z);
    A[6] += w * bflo(q.w); A[7] += w * bfhi(q.w);
}

__global__ __launch_bounds__(256) void k_aggregate(const unsigned short* __restrict__ Hb,
                                                   const float* __restrict__ as_, const float* __restrict__ ad_,
                                                   const int* __restrict__ cnt, const int* __restrict__ bucket,
                                                   const void* __restrict__ bias, int layer,
                                                   const int* __restrict__ flags,
                                                   void* __restrict__ outp, int N) {
    int fx = flags[0];
    int n = blockIdx.x * 4 + (threadIdx.x >> 6);
    if (n >= N) return;
    int deg = cnt[n * 16];
    if (deg > CAP) return;           // handled by k_spillfix
    int lane = threadIdx.x & 63;
    int g = lane >> 4;
    int gl = lane & 15;              // owns channels [gl*8, gl*8+8) of each head
    const int* eb = bucket + n * CAP;
    float2 adv = *(const float2*)(ad_ + 2 * n);
    float ad0 = adv.x, ad1 = adv.y;

    // logits (single sweep: deg <= 48 <= 64 lanes)
    bool act = lane < deg;
    int s = 0; float l0 = -1e30f, l1 = -1e30f;
    if (act) {
        s = eb[lane]; if ((unsigned)s >= (unsigned)N) s = 0;
        float2 av = *(const float2*)(as_ + 2 * s);
        l0 = leaky(av.x + ad0); l1 = leaky(av.y + ad1);
    }
    // max-sub is mathematically redundant (alpha = exp(l)/sum exp(l)); skip the 12-bpermute
    // max reduction unless logits are large enough to overflow exp (never for sane inputs).
    float m0 = 0.f, m1 = 0.f;
    if (__any(fmaxf(l0, l1) > 30.f)) {
        m0 = l0; m1 = l1;
#pragma unroll
        for (int m = 1; m < 64; m <<= 1) { m0 = fmaxf(m0, __shfl_xor(m0, m)); m1 = fmaxf(m1, __shfl_xor(m1, m)); }
    }
    float w0 = act ? __expf(l0 - m0) : 0.f;   // weight==0 for lanes >= deg
    float w1 = act ? __expf(l1 - m1) : 0.f;
    // z sum-reduce DEFERRED to after the gather loop (only needed in epilogue)

    // R10 gather: single prefetch slot, divergent-while, exact trip count
    float acc0[8] = {0,0,0,0,0,0,0,0}, acc1[8] = {0,0,0,0,0,0,0,0};
    int e = g;
    bool v = e < deg;
    float wq0 = __shfl(w0, e), wq1 = __shfl(w1, e);
    int sq = __shfl(s, e);
    uint4 q0, q1;
    if (v) {
        const unsigned short* row = Hb + ((size_t)sq << 8);
        q0 = *(const uint4*)(row + gl * 8);
        q1 = *(const uint4*)(row + 128 + gl * 8);
    }
    while (v) {
        int en = e + 4;
        bool vn = en < deg;
        float wn0 = __shfl(w0, en & 63), wn1 = __shfl(w1, en & 63);
        int sn = __shfl(s, en & 63);
        uint4 p0, p1;
        if (vn) {
            const unsigned short* row = Hb + ((size_t)sn << 8);
            p0 = *(const uint4*)(row + gl * 8);
            p1 = *(const uint4*)(row + 128 + gl * 8);
        }
        acc8(acc0, wq0, q0);
        acc8(acc1, wq1, q1);
        e = en; v = vn; wq0 = wn0; wq1 = wn1; q0 = p0; q1 = p1;
    }

    // deferred softmax denominator
    float z0 = w0, z1 = w1;
#pragma unroll
    for (int m = 1; m < 64; m <<= 1) { z0 += __shfl_xor(z0, m); z1 += __shfl_xor(z1, m); }
    float inv0 = 1.f / (z0 + 1e-16f), inv1 = 1.f / (z1 + 1e-16f);
#pragma unroll
    for (int k = 0; k < 8; k++) {
        acc0[k] += __shfl_xor(acc0[k], 16); acc0[k] += __shfl_xor(acc0[k], 32);
        acc1[k] += __shfl_xor(acc1[k], 16); acc1[k] += __shfl_xor(acc1[k], 32);
    }

    float vv[8];
    if (fx) {
        const float* bf = (const float*)bias + layer * 128 + gl * 8;
#pragma unroll
        for (int k = 0; k < 8; k++) vv[k] = 0.5f * (acc0[k] * inv0 + acc1[k] * inv1) + bf[k];
    } else {
        const unsigned short* bh = (const unsigned short*)bias + layer * 128 + gl * 8;
        uint4 bv = *(const uint4*)bh;
        float bfv[8] = { bflo(bv.x), bfhi(bv.x), bflo(bv.y), bfhi(bv.y),
                         bflo(bv.z), bfhi(bv.z), bflo(bv.w), bfhi(bv.w) };
#pragma unroll
        for (int k = 0; k < 8; k++) vv[k] = 0.5f * (acc0[k] * inv0 + acc1[k] * inv1) + bfv[k];
    }

    float ss = 0.f;
#pragma unroll
    for (int k = 0; k < 8; k++) ss += vv[k] * vv[k];
#pragma unroll
    for (int m = 1; m < 16; m <<= 1) ss += __shfl_xor(ss, m);
    float inv = 1.f / fmaxf(sqrtf(ss), 1e-12f);

    if (lane < 16) {
        if (fx) {
            float* op = (float*)outp + (size_t)n * 128 + gl * 8;
            float4 o0 = { vv[0] * inv, vv[1] * inv, vv[2] * inv, vv[3] * inv };
            float4 o1 = { vv[4] * inv, vv[5] * inv, vv[6] * inv, vv[7] * inv };
            *(float4*)op = o0;
            *(float4*)(op + 4) = o1;
        } else {
            unsigned short* op = (unsigned short*)outp + (size_t)n * 128 + gl * 8;
            uint4 pk;
            pk.x = (unsigned int)f2bf(vv[0] * inv) | ((unsigned int)f2bf(vv[1] * inv) << 16);
            pk.y = (unsigned int)f2bf(vv[2] * inv) | ((unsigned int)f2bf(vv[3] * inv) << 16);
            pk.z = (unsigned int)f2bf(vv[4] * inv) | ((unsigned int)f2bf(vv[5] * inv) << 16);
            pk.w = (unsigned int)f2bf(vv[6] * inv) | ((unsigned int)f2bf(vv[7] * inv) << 16);
            *(uint4*)op = pk;
        }
    }
}

// ---------------- spill fix: only nodes with deg > CAP (statistically never) ----------------
__global__ __launch_bounds__(256) void k_spillfix(const unsigned short* __restrict__ Hb,
                                                  const float* __restrict__ as_, const float* __restrict__ ad_,
                                                  const int* __restrict__ cnt, const int* __restrict__ bucket,
                                                  const int* __restrict__ spill, const int* __restrict__ flags,
                                                  const void* __restrict__ bias, int layer,
                                                  void* __restrict__ outp, int N) {
    if (flags[2] == 0) return;       // no spills anywhere: hot kernel covered every node
    int fx = flags[0];
    int n = blockIdx.x * 4 + (threadIdx.x >> 6);
    if (n >= N) return;
    int deg = cnt[n * 16];
    if (deg <= CAP) return;          // hot kernel handled it
    int lane = threadIdx.x & 63;
    int g = lane >> 4;
    int gl = lane & 15;
    const int* eb = bucket + n * CAP;
    int sc = flags[2]; if (sc > SPILLCAP) sc = SPILLCAP;
    float2 adv = *(const float2*)(ad_ + 2 * n);
    float ad0 = adv.x, ad1 = adv.y;

    float m0 = -1e30f, m1 = -1e30f;
    for (int i = lane; i < CAP; i += 64) {
        int s = eb[i]; if ((unsigned)s >= (unsigned)N) s = 0;
        float2 av = *(const float2*)(as_ + 2 * s);
        m0 = fmaxf(m0, leaky(av.x + ad0));
        m1 = fmaxf(m1, leaky(av.y + ad1));
    }
    for (int i = lane; i < sc; i += 64) {
        if (spill[2 * i] == n) {
            int s = spill[2 * i + 1]; if ((unsigned)s >= (unsigned)N) s = 0;
            float2 av = *(const float2*)(as_ + 2 * s);
            m0 = fmaxf(m0, leaky(av.x + ad0));
            m1 = fmaxf(m1, leaky(av.y + ad1));
        }
    }
#pragma unroll
    for (int m = 1; m < 64; m <<= 1) { m0 = fmaxf(m0, __shfl_xor(m0, m)); m1 = fmaxf(m1, __shfl_xor(m1, m)); }

    float acc0[8] = {0,0,0,0,0,0,0,0}, acc1[8] = {0,0,0,0,0,0,0,0};
    float z0 = 0.f, z1 = 0.f;
    {
        bool act = lane < CAP;
        int s = 0; float w0 = 0.f, w1 = 0.f;
        if (act) {
            s = eb[lane]; if ((unsigned)s >= (unsigned)N) s = 0;
            float2 av = *(const float2*)(as_ + 2 * s);
            w0 = __expf(leaky(av.x + ad0) - m0);
            w1 = __expf(leaky(av.y + ad1) - m1);
            z0 += w0; z1 += w1;
        }
        for (int j = 0; 4 * j < CAP; j++) {
            int e = 4 * j + g;
            int sq    = __shfl(s, e);
            float wq0 = __shfl(w0, e);
            float wq1 = __shfl(w1, e);
            if (e < CAP) {
                const unsigned short* row = Hb + ((size_t)sq << 8);
                uint4 q0 = *(const uint4*)(row + gl * 8);
                uint4 q1 = *(const uint4*)(row + 128 + gl * 8);
                acc8(acc0, wq0, q0);
                acc8(acc1, wq1, q1);
            }
        }
    }
    for (int i = 0; i < sc; i++) {
        int d = spill[2 * i];
        if (d != n) continue;
        int s = spill[2 * i + 1]; if ((unsigned)s >= (unsigned)N) s = 0;
        float2 av = *(const float2*)(as_ + 2 * s);
        float w0 = __expf(leaky(av.x + ad0) - m0);
        float w1 = __expf(leaky(av.y + ad1) - m1);
        if (lane == 0) { z0 += w0; z1 += w1; }
        if (g == 0) {
            const unsigned short* row = Hb + ((size_t)s << 8);
            uint4 q0 = *(const uint4*)(row + gl * 8);
            uint4 q1 = *(const uint4*)(row + 128 + gl * 8);
            acc8(acc0, w0, q0);
            acc8(acc1, w1, q1);
        }
    }
#pragma unroll
    for (int m = 1; m < 64; m <<= 1) { z0 += __shfl_xor(z0, m); z1 += __shfl_xor(z1, m); }

    float inv0 = 1.f / (z0 + 1e-16f), inv1 = 1.f / (z1 + 1e-16f);
#pragma unroll
    for (int k = 0; k < 8; k++) {
        acc0[k] += __shfl_xor(acc0[k], 16); acc0[k] += __shfl_xor(acc0[k], 32);
        acc1[k] += __shfl_xor(acc1[k], 16); acc1[k] += __shfl_xor(acc1[k], 32);
    }
    float vv[8];
    if (fx) {
        const float* bf = (const float*)bias + layer * 128 + gl * 8;
#pragma unroll
        for (int k = 0; k < 8; k++) vv[k] = 0.5f * (acc0[k] * inv0 + acc1[k] * inv1) + bf[k];
    } else {
        const unsigned short* bh = (const unsigned short*)bias + layer * 128 + gl * 8;
        uint4 bv = *(const uint4*)bh;
        float bfv[8] = { bflo(bv.x), bfhi(bv.x), bflo(bv.y), bfhi(bv.y),
                         bflo(bv.z), bfhi(bv.z), bflo(bv.w), bfhi(bv.w) };
#pragma unroll
        for (int k = 0; k < 8; k++) vv[k] = 0.5f * (acc0[k] * inv0 + acc1[k] * inv1) + bfv[k];
    }
    float ss = 0.f;
#pragma unroll
    for (int k = 0; k < 8; k++) ss += vv[k] * vv[k];
#pragma unroll
    for (int m = 1; m < 16; m <<= 1) ss += __shfl_xor(ss, m);
    float inv = 1.f / fmaxf(sqrtf(ss), 1e-12f);
    if (lane < 16) {
        if (fx) {
            float* op = (float*)outp + (size_t)n * 128 + gl * 8;
            float4 o0 = { vv[0] * inv, vv[1] * inv, vv[2] * inv, vv[3] * inv };
            float4 o1 = { vv[4] * inv, vv[5] * inv, vv[6] * inv, vv[7] * inv };
            *(float4*)op = o0;
            *(float4*)(op + 4) = o1;
        } else {
            unsigned short* op = (unsigned short*)outp + (size_t)n * 128 + gl * 8;
            uint4 pk;
            pk.x = (unsigned int)f2bf(vv[0] * inv) | ((unsigned int)f2bf(vv[1] * inv) << 16);
            pk.y = (unsigned int)f2bf(vv[2] * inv) | ((unsigned int)f2bf(vv[3] * inv) << 16);
            pk.z = (unsigned int)f2bf(vv[4] * inv) | ((unsigned int)f2bf(vv[5] * inv) << 16);
            pk.w = (unsigned int)f2bf(vv[6] * inv) | ((unsigned int)f2bf(vv[7] * inv) << 16);
            *(uint4*)op = pk;
        }
    }
}

extern "C" void kernel_launch(void* const* d_in, const int* in_sizes, int n_in,
                              void* d_out, int out_size, void* d_ws, size_t ws_size,
                              hipStream_t stream) {
    const void* x    = d_in[0];
    const int*  ei   = (const int*)d_in[1];
    const void* W    = d_in[2];
    const void* atts = d_in[3];
    const void* attd = d_in[4];
    const void* bias = d_in[5];

    int N = in_sizes[0] / 128;
    int E = in_sizes[1] / 2;

    char* p = (char*)d_ws;
    auto alloc = [&](size_t bytes) -> char* {
        char* q = p; p += (bytes + 255) & ~(size_t)255; return q;
    };
    int* flags   = (int*)alloc(256);                                   // [0]=fx [1]=is64 [2]=spillcnt
    int* cnt     = (int*)alloc((size_t)N * 64);                        // 1 counter per 64B line
    float* as_   = (float*)alloc((size_t)N * 2 * 4);
    float* ad_   = (float*)alloc((size_t)N * 2 * 4);
    unsigned short* wt = (unsigned short*)alloc(2 * 256 * 128 * 2);
    int* spill   = (int*)alloc((size_t)SPILLCAP * 2 * 4);              // 512 KB
    int* bucket  = (int*)alloc((size_t)N * CAP * 4);                   // 9.6 MB
    unsigned short* hbuf = (unsigned short*)alloc((size_t)N * 256 * 2);// 25.6 MB
    // total ~40 MB

    k_probe_zero<<<(N + 255) / 256, 256, 0, stream>>>((const unsigned int*)x, ei, flags, cnt, N);
    int work = E + N; if (work < 65536) work = 65536;
    k_bucket<<<(work + 1023) / 1024, 256, 0, stream>>>(ei, E, N, flags, cnt, bucket, spill, W, wt);

    int mtiles = (N + 31) / 32;
    int ngrp = (N + 3) / 4;
    for (int l = 0; l < 2; l++) {
        const void* xin = (l == 0) ? x : (const void*)d_out;
        k_gemm_alpha<<<mtiles, 256, 0, stream>>>(xin, wt + l * 32768, atts, attd, l,
                                                 hbuf, as_, ad_, N, flags);
        k_aggregate<<<ngrp, 256, 0, stream>>>(hbuf, as_, ad_, cnt, bucket,
                                              bias, l, flags, d_out, N);
        k_spillfix<<<ngrp, 256, 0, stream>>>(hbuf, as_, ad_, cnt, bucket, spill, flags,
                                             bias, l, d_out, N);
    }
}